// Round 6
// baseline (211.571 us; speedup 1.0000x reference)
//
#include <hip/hip_runtime.h>
#include <hip/hip_bf16.h>

// Problem constants
#define B_ 4
#define DIM_ 256
#define N_ 2048
#define M_ 2048
#define HEADS_ 8
#define DHEAD_ 64
#define DINNER_ 512

typedef __attribute__((ext_vector_type(8))) short short8;
typedef __attribute__((ext_vector_type(4))) short short4v;
typedef __attribute__((ext_vector_type(4))) float floatx4;
typedef __attribute__((ext_vector_type(4))) _Float16 half4;
typedef __attribute__((ext_vector_type(8))) _Float16 half8;

#if defined(__has_builtin)
#if __has_builtin(__builtin_amdgcn_global_load_lds)
#define HAS_DMA 1
#endif
#endif

typedef __attribute__((address_space(1))) const void gvoid_t;
typedef __attribute__((address_space(3))) void lvoid_t;

// |C2| = 0.125 * log2(e); folded into Q and K bf16 planes so attention's
// inner loop computes pv = exp2(-sqrt(d2')) with zero extra multiplies.
#define CQ_ 0.18033688011112042f
#define NEG2CQ_ (-0.36067376022224084f)
#define EPS2_ 3.25213893e-14f  // 1e-12 * CQ^2

__device__ inline short bf16r(float x) {  // RNE f32->bf16 (bit form)
  unsigned u = __float_as_uint(x);
  unsigned r = (u + 0x7fffu + ((u >> 16) & 1u)) >> 16;
  return (short)r;
}
__device__ inline float bf2f(short b) {
  return __uint_as_float(((unsigned)(unsigned short)b) << 16);
}

// ---------------------------------------------------------------------------
// Kernel 0 (fused preproc): bid<768 -> W split (whi/wlo bf16 planes of
// W*gamma); bid>=768 -> channel RMSNorm -> bf16 transposed for fmap+context.
// One launch instead of two (graph serial-overhead cut).
// ---------------------------------------------------------------------------
__global__ __launch_bounds__(256) void preproc_kernel(
    const float* __restrict__ Wq, const float* __restrict__ Wkv,
    const float* __restrict__ Wout, const float* __restrict__ gamma,
    const float* __restrict__ gctx, short* __restrict__ whi,
    short* __restrict__ wlo, const float* __restrict__ xf,
    const float* __restrict__ xc, short* __restrict__ xtf,
    short* __restrict__ xtc) {
  const int bid = blockIdx.x;
  const int tid = threadIdx.x;

  __shared__ float red[4][64];
  __shared__ float scl[64];
  __shared__ float t[64][65];

  if (bid < 768) {
    // ---- W split part ----
    const int y = bid >> 8;  // 0..2
    const int gsz[3] = {32768, 65536, 32768};  // float4 groups per matrix
    const int goff[3] = {0, 131072, 393216};   // element offset in planes
    int gidx = (bid & 255) * 256 + tid;
    if (gidx >= gsz[y]) return;
    const float* W = (y == 0) ? Wq : (y == 1) ? Wkv : Wout;
    const int cmask = (y == 2) ? 511 : 255;
    int e0 = gidx * 4;
    int c = e0 & cmask;
    float4 wv = *(const float4*)&W[e0];
    if (y < 2) {
      const float* g = (y == 0) ? gamma : gctx;
      float4 g4 = *(const float4*)&g[c];
      wv.x *= g4.x; wv.y *= g4.y; wv.z *= g4.z; wv.w *= g4.w;
    }
    float vv[4] = {wv.x, wv.y, wv.z, wv.w};
    short4v hi, lo;
#pragma unroll
    for (int e = 0; e < 4; ++e) {
      short hb = bf16r(vv[e]);
      hi[e] = hb;
      lo[e] = bf16r(vv[e] - bf2f(hb));
    }
    *(short4v*)&whi[goff[y] + e0] = hi;
    *(short4v*)&wlo[goff[y] + e0] = lo;
    return;
  }

  // ---- colnorm part ----
  const int cid = bid - 768;              // 0..255
  const int NN = 2048;
  const int z = cid >> 7;                 // 0..1
  const int b = (cid >> 5) & 3;           // 0..3
  const int xblk = cid & 31;              // 0..31
  const float* x = (z == 0) ? xf : xc;
  short* xt = (z == 0) ? xtf : xtc;
  const int tx = tid & 63, ty = tid >> 6;
  const int n0 = xblk * 64, n = n0 + tx;
  const float* xb = x + (size_t)b * 256 * NN;

  float ssq = 0.f;
  for (int c = ty; c < 256; c += 4) {
    float v = xb[(size_t)c * NN + n];
    ssq += v * v;
  }
  red[ty][tx] = ssq;
  __syncthreads();
  if (ty == 0) {
    float s = red[0][tx] + red[1][tx] + red[2][tx] + red[3][tx];
    scl[tx] = 16.0f / fmaxf(sqrtf(s), 1e-12f);
  }
  const int row = tid >> 2, cg = tid & 3;
  for (int c0 = 0; c0 < 256; c0 += 64) {
    __syncthreads();
    for (int cc = ty; cc < 64; cc += 4) t[cc][tx] = xb[(size_t)(c0 + cc) * NN + n];
    __syncthreads();
    float sc = scl[row];
    short8 o0v, o1v;
#pragma unroll
    for (int e = 0; e < 8; ++e) {
      o0v[e] = bf16r(t[cg * 16 + e][row] * sc);
      o1v[e] = bf16r(t[cg * 16 + 8 + e][row] * sc);
    }
    size_t base = ((size_t)b * NN + n0 + row) * 256 + c0 + cg * 16;
    *(short8*)&xt[base] = o0v;
    *(short8*)&xt[base + 8] = o1v;
  }
}

// ---------------------------------------------------------------------------
// Kernel 2: fused Q + KV projection MFMA GEMM (one launch).
// grid (16, 12, B): y<4 -> q-proj (o0=y*128, X=fmap_t, out=qb bf16 [b][n][512],
// scaled by CQ); y>=4 -> kv-proj (o0=(y-4)*128, X=ctx_t): o0<512 K-part
// (-2*CQ scale, swizzled tiles + fused k2m/mask -> k2m = CQ^2*k2), else V-part
// (f16 permuted+swizzled tiles).
// ---------------------------------------------------------------------------
__global__ __launch_bounds__(256) void qkv_gemm_kernel(
    const short* __restrict__ whi, const short* __restrict__ wlo,
    const short* __restrict__ fmap_t, const short* __restrict__ ctx_t,
    short* __restrict__ qb, short* __restrict__ kc, _Float16* __restrict__ vc,
    const int* __restrict__ maskp, float* __restrict__ k2m) {
  const int b = blockIdx.z;
  const int y = blockIdx.y;
  const bool isq = (y < 4);
  const int o0 = (isq ? y : y - 4) * 128;
  const int n0 = blockIdx.x * 128;
  const short* Wh = whi + (isq ? 0 : 131072);
  const short* Wl = wlo + (isq ? 0 : 131072);
  const short* Xt = isq ? fmap_t : ctx_t;

  const int tid = threadIdx.x;
  const int w = tid >> 6, l = tid & 63, quad = l >> 4, l15 = l & 15;
  const int wo = (w >> 1) * 64, wn = (w & 1) * 64;

  __shared__ __align__(16) short Wa[2][128][40];
  __shared__ __align__(16) short Xb[128][40];

  floatx4 acc[4][4];
#pragma unroll
  for (int ot = 0; ot < 4; ++ot)
#pragma unroll
    for (int nt = 0; nt < 4; ++nt)
#pragma unroll
      for (int r = 0; r < 4; ++r) acc[ot][nt][r] = 0.f;

  for (int c0 = 0; c0 < 256; c0 += 32) {
    __syncthreads();
#pragma unroll
    for (int it = 0; it < 2; ++it) {
      int lin = tid + it * 256;
      int row = lin >> 2, sg = (lin & 3) * 8;
      size_t src = (size_t)(o0 + row) * 256 + c0 + sg;
      *(short8*)&Wa[0][row][sg] = *(const short8*)&Wh[src];
      *(short8*)&Wa[1][row][sg] = *(const short8*)&Wl[src];
    }
#pragma unroll
    for (int it = 0; it < 2; ++it) {
      int lin = tid + it * 256;
      int nn = lin >> 2, sg = (lin & 3) * 8;
      *(short8*)&Xb[nn][sg] =
          *(const short8*)&Xt[((size_t)b * 2048 + n0 + nn) * 256 + c0 + sg];
    }
    __syncthreads();

    short8 ah[4], al[4], bx[4];
#pragma unroll
    for (int ot = 0; ot < 4; ++ot) {
      ah[ot] = *(const short8*)&Wa[0][wo + 16 * ot + l15][8 * quad];
      al[ot] = *(const short8*)&Wa[1][wo + 16 * ot + l15][8 * quad];
    }
#pragma unroll
    for (int nt = 0; nt < 4; ++nt)
      bx[nt] = *(const short8*)&Xb[wn + 16 * nt + l15][8 * quad];
#pragma unroll
    for (int ot = 0; ot < 4; ++ot)
#pragma unroll
      for (int nt = 0; nt < 4; ++nt) {
        acc[ot][nt] =
            __builtin_amdgcn_mfma_f32_16x16x32_bf16(al[ot], bx[nt], acc[ot][nt], 0, 0, 0);
        acc[ot][nt] =
            __builtin_amdgcn_mfma_f32_16x16x32_bf16(ah[ot], bx[nt], acc[ot][nt], 0, 0, 0);
      }
  }

  if (isq) {
#pragma unroll
    for (int nt = 0; nt < 4; ++nt) {
      int n = n0 + wn + 16 * nt + l15;
      size_t base = ((size_t)b * 2048 + n) * 512;
#pragma unroll
      for (int ot = 0; ot < 4; ++ot) {
        int o = o0 + wo + 16 * ot + 4 * quad;
        short4v pk;
#pragma unroll
        for (int r = 0; r < 4; ++r) pk[r] = bf16r(CQ_ * acc[ot][nt][r]);
        *(short4v*)&qb[base + o] = pk;
      }
    }
  } else if (o0 < 512) {
    // K part: one head per wave (64 channels), -2*CQ scale, swizzled tiles + k2.
    const int head = (o0 + wo) >> 6;
    const int bh = b * 8 + head;
    float k2p[4] = {0.f, 0.f, 0.f, 0.f};
#pragma unroll
    for (int nt = 0; nt < 4; ++nt) {
      int m = n0 + wn + 16 * nt + l15;
      int chunk = m >> 6, mrow = m & 63;
      size_t tbase = (((size_t)bh * 32 + chunk) * 64 + mrow) * 64;
      int sw = mrow & 7;
#pragma unroll
      for (int ot = 0; ot < 4; ++ot) {
        int d0 = 16 * ot + 4 * quad;
        short4v pk;
#pragma unroll
        for (int r = 0; r < 4; ++r) {
          short pv = bf16r(NEG2CQ_ * acc[ot][nt][r]);
          pk[r] = pv;
          float kr = bf2f(pv);
          k2p[nt] += kr * kr;
        }
        *(short4v*)&kc[tbase + (size_t)(((d0 >> 3) ^ sw) << 3) + (d0 & 7)] = pk;
      }
    }
#pragma unroll
    for (int nt = 0; nt < 4; ++nt) {
      float s = k2p[nt];
      s += __shfl_xor(s, 16);
      s += __shfl_xor(s, 32);
      if (quad == 0) {
        int m = n0 + wn + 16 * nt + l15;
        int mv = maskp[b * 2048 + m];
        k2m[(size_t)bh * 2048 + m] = mv ? 0.25f * s : __builtin_inff();
      }
    }
  } else {
    // V part: f16, column permute (PV A-frag order) + group swizzle.
    const int chv = o0 - 512 + wo;  // base channel for this wave (one head)
    const int bh = b * 8 + (chv >> 6);
#pragma unroll
    for (int nt = 0; nt < 4; ++nt) {
      int j = n0 + wn + 16 * nt + l15;
      int chunk = j >> 6, jr = j & 63;
      int jrem = jr & 31;
      int colp = 32 * (jr >> 5) + ((jrem >> 2) & 3) * 8 + (jrem >> 4) * 4 +
                 (jrem & 3);
      size_t cbase = ((size_t)bh * 32 + chunk) * 4096;
#pragma unroll
      for (int ot = 0; ot < 4; ++ot)
#pragma unroll
        for (int r = 0; r < 4; ++r) {
          int drow = (chv + 16 * ot + 4 * quad + r) & 63;
          vc[cbase + drow * 64 + (((colp >> 3) ^ (drow & 7)) << 3) +
             (colp & 7)] = (_Float16)acc[ot][nt][r];
        }
    }
  }
}

// ---------------------------------------------------------------------------
// Kernel 3: L2-distance flash attention (R3 structure + k2 reg prefetch).
// 8 waves / 512 threads per block: wave (wr,jh) = (w>>1, w&1); wr picks the
// 16 q-rows, jh picks the j-half (32 of 64) of each chunk. 8 waves/SIMD at
// 32KB LDS (4 blocks/CU). |C2| pre-folded into q/k/k2m, so inner loop is
// exp2(-sqrt(max(a,eps))). PV is ONE mfma_f32_16x16x32_f16 per dt.
// k2 is register-prefetched one chunk ahead (takes the ~200cy L2 load off
// the head of the QK dependency chain). VGPR budget: ~40 of the hard 64
// (8 waves/SIMD). R2/R5 lesson: cross-chunk MFMA reordering at source level
// REGRESSES (barrier keeps waves phase-locked; compiler schedule perturbed);
// keep the simple QK->softmax->PV order.
// ---------------------------------------------------------------------------
__global__ __launch_bounds__(512, 8) void attn_kernel(
    const short* __restrict__ qb, const short* __restrict__ kc,
    const _Float16* __restrict__ vc, const float* __restrict__ k2m,
    short* __restrict__ attn_t) {
  const int bid = blockIdx.x;
  const int rr = bid & 7, qq = bid >> 3;  // rr ~ XCD
  const int bh = rr * 4 + (qq >> 5);      // 4 bh per XCD
  const int iblk = qq & 31;
  const int h = bh & 7, b = bh >> 3;
  const int i0 = iblk * 64;

  const int tid = threadIdx.x;
  const int w = tid >> 6, l = tid & 63, quad = l >> 4, l15 = l & 15;
  const int wr = w >> 1, jh = w & 1;

  __shared__ __align__(16) short sbuf[2][2][4096];  // [K/V][dbuf][8KB]

  const short* qrow =
      qb + ((size_t)b * 2048 + i0 + 16 * wr + l15) * 512 + h * 64;
  const short* kcb = kc + (size_t)bh * 32 * 4096;
  const _Float16* vcb = vc + (size_t)bh * 32 * 4096;
  const float* k2b = k2m + (size_t)bh * 2048;

  // Q^T B-fragments (n=i=l15, k=d=8*quad+jj) + q2 (per-lane scalar, CQ^2-scaled)
  short8 qa0 = *(const short8*)&qrow[8 * quad];
  short8 qa1 = *(const short8*)&qrow[32 + 8 * quad];
  float q2p = 0.f;
#pragma unroll
  for (int jj = 0; jj < 8; ++jj) {
    float f0 = bf2f(qa0[jj]), f1 = bf2f(qa1[jj]);
    q2p += f0 * f0 + f1 * f1;
  }
  q2p += __shfl_xor(q2p, 16);
  q2p += __shfl_xor(q2p, 32);
  const float q2c = q2p;

  floatx4 accO[4];
#pragma unroll
  for (int dt = 0; dt < 4; ++dt)
#pragma unroll
    for (int r = 0; r < 4; ++r) accO[dt][r] = 0.f;
  float lsum = 0.f;

  const int sx = l15 & 7;  // swizzle key

  auto stage = [&](int c, int p) {
    const short* ks = kcb + (size_t)c * 4096 + w * 512 + l * 8;
    const _Float16* vs = vcb + (size_t)c * 4096 + w * 512 + l * 8;
#ifdef HAS_DMA
    __builtin_amdgcn_global_load_lds((gvoid_t*)ks,
                                     (lvoid_t*)&sbuf[0][p][w * 512], 16, 0, 0);
    __builtin_amdgcn_global_load_lds((gvoid_t*)vs,
                                     (lvoid_t*)&sbuf[1][p][w * 512], 16, 0, 0);
#else
    *(short8*)&sbuf[0][p][w * 512 + l * 8] = *(const short8*)ks;
    *(half8*)&((_Float16*)sbuf[1][p])[w * 512 + l * 8] = *(const half8*)vs;
#endif
  };

  // k2 prefetch for chunk 0
  float4 k2pf0 = *(const float4*)&k2b[jh * 32 + 4 * quad];
  float4 k2pf1 = *(const float4*)&k2b[jh * 32 + 16 + 4 * quad];

  stage(0, 0);
  for (int c = 0; c < 32; ++c) {
    __syncthreads();  // drains chunk-c DMA (vmcnt(0) before barrier)
    if (c < 31) stage(c + 1, (c + 1) & 1);
    const int p = c & 1;

    float4 k2c0 = k2pf0, k2c1 = k2pf1;
    if (c < 31) {
      k2pf0 = *(const float4*)&k2b[(c + 1) * 64 + jh * 32 + 4 * quad];
      k2pf1 = *(const float4*)&k2b[(c + 1) * 64 + jh * 32 + 16 + 4 * quad];
    }

    half8 pb;
#pragma unroll
    for (int jt = 0; jt < 2; ++jt) {
      float4 k2v = jt ? k2c1 : k2c0;
      const short* kr = &sbuf[0][p][(jh * 32 + 16 * jt + l15) * 64];
      short8 k0 = *(const short8*)&kr[(quad ^ sx) << 3];
      short8 k1 = *(const short8*)&kr[((quad + 4) ^ sx) << 3];
      floatx4 a;  // accumulator pre-loaded with q2 + k2 (both CQ^2-scaled)
      a[0] = q2c + k2v.x;
      a[1] = q2c + k2v.y;
      a[2] = q2c + k2v.z;
      a[3] = q2c + k2v.w;
      __builtin_amdgcn_s_setprio(1);
      a = __builtin_amdgcn_mfma_f32_16x16x32_bf16(k0, qa0, a, 0, 0, 0);
      a = __builtin_amdgcn_mfma_f32_16x16x32_bf16(k1, qa1, a, 0, 0, 0);
      __builtin_amdgcn_s_setprio(0);
#pragma unroll
      for (int r = 0; r < 4; ++r) {
        float s = __builtin_amdgcn_sqrtf(fmaxf(a[r], EPS2_));
        float pv = __builtin_amdgcn_exp2f(-s);  // neg is a free input modifier
        lsum += pv;
        pb[4 * jt + r] = (_Float16)pv;
      }
    }

    __builtin_amdgcn_s_setprio(1);
#pragma unroll
    for (int dt = 0; dt < 4; ++dt) {
      const _Float16* vr = (const _Float16*)&sbuf[1][p][(16 * dt + l15) * 64];
      half8 hh = *(const half8*)&vr[((quad + 4 * jh) ^ sx) << 3];
      accO[dt] =
          __builtin_amdgcn_mfma_f32_16x16x32_f16(hh, pb, accO[dt], 0, 0, 0);
    }
    __builtin_amdgcn_s_setprio(0);
  }

  // Merge jh=1 partials into jh=0 through LDS (buffers are dead now).
  __syncthreads();
  float* scr = (float*)sbuf;  // 4 waves * 64 lanes * 17 floats = 17408B < 32KB
  const int sidx = (wr * 64 + l) * 17;
  if (jh) {
#pragma unroll
    for (int dt = 0; dt < 4; ++dt)
#pragma unroll
      for (int r = 0; r < 4; ++r) scr[sidx + dt * 4 + r] = accO[dt][r];
    scr[sidx + 16] = lsum;
  }
  __syncthreads();
  if (!jh) {
#pragma unroll
    for (int dt = 0; dt < 4; ++dt)
#pragma unroll
      for (int r = 0; r < 4; ++r) accO[dt][r] += scr[sidx + dt * 4 + r];
    lsum += scr[sidx + 16];
    lsum += __shfl_xor(lsum, 16);
    lsum += __shfl_xor(lsum, 32);
    float rl = 1.0f / lsum;
    size_t base = ((size_t)b * 2048 + i0 + 16 * wr + l15) * 512 + h * 64;
#pragma unroll
    for (int dt = 0; dt < 4; ++dt) {
      short4v pk;
#pragma unroll
      for (int r = 0; r < 4; ++r) pk[r] = bf16r(accO[dt][r] * rl);
      *(short4v*)&attn_t[base + 16 * dt + 4 * quad] = pk;
    }
  }
}

// ---------------------------------------------------------------------------
// Kernel 4: out-projection MFMA GEMM, 64o x 128n tiles (256 blocks = 1/CU).
// Y fp32 [b][256][2048] = sum_c W'[o][c] * attn_t[b][n][c], C=512.
// 4 waves as 2x2: wave tile 32o x 64n, acc[2][4].
// ---------------------------------------------------------------------------
__global__ __launch_bounds__(256) void outproj_kernel(
    const short* __restrict__ whi, const short* __restrict__ wlo,
    const short* __restrict__ Xt, float* __restrict__ Yf) {
  const int b = blockIdx.z;
  const int n0 = blockIdx.x * 128;
  const int o0 = blockIdx.y * 64;
  const int tid = threadIdx.x;
  const int w = tid >> 6, l = tid & 63, quad = l >> 4, l15 = l & 15;
  const int wo = (w >> 1) * 32, wn = (w & 1) * 64;

  __shared__ __align__(16) short Wa[2][64][40];
  __shared__ __align__(16) short Xb[128][40];

  floatx4 acc[2][4];
#pragma unroll
  for (int ot = 0; ot < 2; ++ot)
#pragma unroll
    for (int nt = 0; nt < 4; ++nt)
#pragma unroll
      for (int r = 0; r < 4; ++r) acc[ot][nt][r] = 0.f;

  for (int c0 = 0; c0 < 512; c0 += 32) {
    __syncthreads();
    {
      int row = tid >> 2, sg = (tid & 3) * 8;  // 64 rows x 32c in one pass
      size_t src = (size_t)(o0 + row) * 512 + c0 + sg;
      *(short8*)&Wa[0][row][sg] = *(const short8*)&whi[src];
      *(short8*)&Wa[1][row][sg] = *(const short8*)&wlo[src];
    }
#pragma unroll
    for (int it = 0; it < 2; ++it) {
      int lin = tid + it * 256;
      int nn = lin >> 2, sg = (lin & 3) * 8;
      *(short8*)&Xb[nn][sg] =
          *(const short8*)&Xt[((size_t)b * 2048 + n0 + nn) * 512 + c0 + sg];
    }
    __syncthreads();

    short8 ah[2], al[2], bx[4];
#pragma unroll
    for (int ot = 0; ot < 2; ++ot) {
      ah[ot] = *(const short8*)&Wa[0][wo + 16 * ot + l15][8 * quad];
      al[ot] = *(const short8*)&Wa[1][wo + 16 * ot + l15][8 * quad];
    }
#pragma unroll
    for (int nt = 0; nt < 4; ++nt)
      bx[nt] = *(const short8*)&Xb[wn + 16 * nt + l15][8 * quad];
#pragma unroll
    for (int ot = 0; ot < 2; ++ot)
#pragma unroll
      for (int nt = 0; nt < 4; ++nt) {
        acc[ot][nt] =
            __builtin_amdgcn_mfma_f32_16x16x32_bf16(al[ot], bx[nt], acc[ot][nt], 0, 0, 0);
        acc[ot][nt] =
            __builtin_amdgcn_mfma_f32_16x16x32_bf16(ah[ot], bx[nt], acc[ot][nt], 0, 0, 0);
      }
  }

#pragma unroll
  for (int ot = 0; ot < 2; ++ot)
#pragma unroll
    for (int r = 0; r < 4; ++r) {
      int o = o0 + wo + 16 * ot + 4 * quad + r;
#pragma unroll
      for (int nt = 0; nt < 4; ++nt)
        Yf[((size_t)b * 256 + o) * 2048 + n0 + wn + 16 * nt + l15] =
            acc[ot][nt][r];
    }
}

// ---------------------------------------------------------------------------
extern "C" void kernel_launch(void* const* d_in, const int* in_sizes, int n_in,
                              void* d_out, int out_size, void* d_ws,
                              size_t ws_size, hipStream_t stream) {
  const float* fmap = (const float*)d_in[0];
  const float* context = (const float*)d_in[1];
  const int* mask = (const int*)d_in[2];
  const float* gamma = (const float*)d_in[3];
  const float* gamma_ctx = (const float*)d_in[4];
  const float* Wq = (const float*)d_in[5];
  const float* Wkv = (const float*)d_in[6];
  const float* Wout = (const float*)d_in[7];
  float* out = (float*)d_out;

  char* ws = (char*)d_ws;
  short* fmap_t = (short*)ws;                 // 4 MB
  short* ctx_t = fmap_t + 2097152;            // 4 MB
  short* qb = ctx_t + 2097152;                // 8 MB
  short* kc = qb + 4194304;                   // 8 MB (-2CQ*K, swizzled tiles)
  _Float16* vc = (_Float16*)(kc + 4194304);   // 8 MB (f16, permuted tiles)
  short* attn_t = (short*)(vc + 4194304);     // 8 MB
  float* k2m = (float*)(attn_t + 4194304);    // 256 KB
  short* whi = (short*)(k2m + 65536);         // 1 MB
  short* wlo = whi + 524288;                  // 1 MB

  preproc_kernel<<<dim3(1024), 256, 0, stream>>>(
      Wq, Wkv, Wout, gamma, gamma_ctx, whi, wlo, fmap, context, fmap_t, ctx_t);
  qkv_gemm_kernel<<<dim3(16, 12, B_), 256, 0, stream>>>(
      whi, wlo, fmap_t, ctx_t, qb, kc, vc, mask, k2m);
  attn_kernel<<<dim3(1024), 512, 0, stream>>>(qb, kc, vc, k2m, attn_t);
  outproj_kernel<<<dim3(16, 4, B_), 256, 0, stream>>>(whi + 393216,
                                                      wlo + 393216, attn_t,
                                                      out);
}

// Round 7
// 195.593 us; speedup vs baseline: 1.0817x; 1.0817x over previous
//
#include <hip/hip_runtime.h>
#include <hip/hip_bf16.h>

// Problem constants
#define B_ 4
#define DIM_ 256
#define N_ 2048
#define M_ 2048
#define HEADS_ 8
#define DHEAD_ 64
#define DINNER_ 512

typedef __attribute__((ext_vector_type(8))) short short8;
typedef __attribute__((ext_vector_type(4))) short short4v;
typedef __attribute__((ext_vector_type(4))) float floatx4;
typedef __attribute__((ext_vector_type(4))) _Float16 half4;
typedef __attribute__((ext_vector_type(8))) _Float16 half8;

#if defined(__has_builtin)
#if __has_builtin(__builtin_amdgcn_global_load_lds)
#define HAS_DMA 1
#endif
#endif

typedef __attribute__((address_space(1))) const void gvoid_t;
typedef __attribute__((address_space(3))) void lvoid_t;

// |C2| = 0.125 * log2(e); folded into Q and K bf16 planes so attention's
// inner loop computes pv = exp2(-sqrt(d2')) with zero extra multiplies.
#define CQ_ 0.18033688011112042f
#define NEG2CQ_ (-0.36067376022224084f)
#define EPS2_ 3.25213893e-14f  // 1e-12 * CQ^2

__device__ inline short bf16r(float x) {  // RNE f32->bf16 (bit form)
  unsigned u = __float_as_uint(x);
  unsigned r = (u + 0x7fffu + ((u >> 16) & 1u)) >> 16;
  return (short)r;
}
__device__ inline float bf2f(short b) {
  return __uint_as_float(((unsigned)(unsigned short)b) << 16);
}

// ---------------------------------------------------------------------------
// Kernel 0 (fused preproc): bid<768 -> W split (whi/wlo bf16 planes of
// W*gamma); bid>=768 -> channel RMSNorm -> bf16 transposed for fmap+context.
// ---------------------------------------------------------------------------
__global__ __launch_bounds__(256) void preproc_kernel(
    const float* __restrict__ Wq, const float* __restrict__ Wkv,
    const float* __restrict__ Wout, const float* __restrict__ gamma,
    const float* __restrict__ gctx, short* __restrict__ whi,
    short* __restrict__ wlo, const float* __restrict__ xf,
    const float* __restrict__ xc, short* __restrict__ xtf,
    short* __restrict__ xtc) {
  const int bid = blockIdx.x;
  const int tid = threadIdx.x;

  __shared__ float red[4][64];
  __shared__ float scl[64];
  __shared__ float t[64][65];

  if (bid < 768) {
    // ---- W split part ----
    const int y = bid >> 8;  // 0..2
    const int gsz[3] = {32768, 65536, 32768};  // float4 groups per matrix
    const int goff[3] = {0, 131072, 393216};   // element offset in planes
    int gidx = (bid & 255) * 256 + tid;
    if (gidx >= gsz[y]) return;
    const float* W = (y == 0) ? Wq : (y == 1) ? Wkv : Wout;
    const int cmask = (y == 2) ? 511 : 255;
    int e0 = gidx * 4;
    int c = e0 & cmask;
    float4 wv = *(const float4*)&W[e0];
    if (y < 2) {
      const float* g = (y == 0) ? gamma : gctx;
      float4 g4 = *(const float4*)&g[c];
      wv.x *= g4.x; wv.y *= g4.y; wv.z *= g4.z; wv.w *= g4.w;
    }
    float vv[4] = {wv.x, wv.y, wv.z, wv.w};
    short4v hi, lo;
#pragma unroll
    for (int e = 0; e < 4; ++e) {
      short hb = bf16r(vv[e]);
      hi[e] = hb;
      lo[e] = bf16r(vv[e] - bf2f(hb));
    }
    *(short4v*)&whi[goff[y] + e0] = hi;
    *(short4v*)&wlo[goff[y] + e0] = lo;
    return;
  }

  // ---- colnorm part ----
  const int cid = bid - 768;              // 0..255
  const int NN = 2048;
  const int z = cid >> 7;                 // 0..1
  const int b = (cid >> 5) & 3;           // 0..3
  const int xblk = cid & 31;              // 0..31
  const float* x = (z == 0) ? xf : xc;
  short* xt = (z == 0) ? xtf : xtc;
  const int tx = tid & 63, ty = tid >> 6;
  const int n0 = xblk * 64, n = n0 + tx;
  const float* xb = x + (size_t)b * 256 * NN;

  float ssq = 0.f;
  for (int c = ty; c < 256; c += 4) {
    float v = xb[(size_t)c * NN + n];
    ssq += v * v;
  }
  red[ty][tx] = ssq;
  __syncthreads();
  if (ty == 0) {
    float s = red[0][tx] + red[1][tx] + red[2][tx] + red[3][tx];
    scl[tx] = 16.0f / fmaxf(sqrtf(s), 1e-12f);
  }
  const int row = tid >> 2, cg = tid & 3;
  for (int c0 = 0; c0 < 256; c0 += 64) {
    __syncthreads();
    for (int cc = ty; cc < 64; cc += 4) t[cc][tx] = xb[(size_t)(c0 + cc) * NN + n];
    __syncthreads();
    float sc = scl[row];
    short8 o0v, o1v;
#pragma unroll
    for (int e = 0; e < 8; ++e) {
      o0v[e] = bf16r(t[cg * 16 + e][row] * sc);
      o1v[e] = bf16r(t[cg * 16 + 8 + e][row] * sc);
    }
    size_t base = ((size_t)b * NN + n0 + row) * 256 + c0 + cg * 16;
    *(short8*)&xt[base] = o0v;
    *(short8*)&xt[base + 8] = o1v;
  }
}

// ---------------------------------------------------------------------------
// Kernel 2: fused Q + KV projection MFMA GEMM (one launch).
// grid (16, 12, B): y<4 -> q-proj (o0=y*128, X=fmap_t, out=qb bf16 [b][n][512],
// scaled by CQ); y>=4 -> kv-proj (o0=(y-4)*128, X=ctx_t): o0<512 K-part
// (-2*CQ scale, swizzled tiles + fused k2m/mask -> k2m = CQ^2*k2), else V-part
// (f16 permuted+swizzled tiles).
// R7: K/V epilogues stage each wave's 64x64 tile through LDS (final layout)
// and store with 8 coalesced 1KB instructions, replacing the 2B/8B global
// scatter (V was 64 scalar 2B stores/thread). Same values, same layout ->
// bit-identical output. LDS: Wa/Xb (30.7KB main loop) unioned with 4x9216B
// wave slabs (36.9KB total, 4 blocks/CU; grid needs 3).
// ---------------------------------------------------------------------------
__global__ __launch_bounds__(256) void qkv_gemm_kernel(
    const short* __restrict__ whi, const short* __restrict__ wlo,
    const short* __restrict__ fmap_t, const short* __restrict__ ctx_t,
    short* __restrict__ qb, short* __restrict__ kc, _Float16* __restrict__ vc,
    const int* __restrict__ maskp, float* __restrict__ k2m) {
  const int b = blockIdx.z;
  const int y = blockIdx.y;
  const bool isq = (y < 4);
  const int o0 = (isq ? y : y - 4) * 128;
  const int n0 = blockIdx.x * 128;
  const short* Wh = whi + (isq ? 0 : 131072);
  const short* Wl = wlo + (isq ? 0 : 131072);
  const short* Xt = isq ? fmap_t : ctx_t;

  const int tid = threadIdx.x;
  const int w = tid >> 6, l = tid & 63, quad = l >> 4, l15 = l & 15;
  const int wo = (w >> 1) * 64, wn = (w & 1) * 64;

  // Union: main loop Wa[2][128][40] (20480B) + Xb[128][40] (10240B) = 30720B;
  // epilogue 4 wave slabs of [64][72] shorts (9216B each) = 36864B.
  __shared__ __align__(16) char smem[36864];
  short (*Wa)[128][40] = (short (*)[128][40])smem;
  short (*Xb)[40] = (short (*)[40])(smem + 20480);

  floatx4 acc[4][4];
#pragma unroll
  for (int ot = 0; ot < 4; ++ot)
#pragma unroll
    for (int nt = 0; nt < 4; ++nt)
#pragma unroll
      for (int r = 0; r < 4; ++r) acc[ot][nt][r] = 0.f;

  for (int c0 = 0; c0 < 256; c0 += 32) {
    __syncthreads();
#pragma unroll
    for (int it = 0; it < 2; ++it) {
      int lin = tid + it * 256;
      int row = lin >> 2, sg = (lin & 3) * 8;
      size_t src = (size_t)(o0 + row) * 256 + c0 + sg;
      *(short8*)&Wa[0][row][sg] = *(const short8*)&Wh[src];
      *(short8*)&Wa[1][row][sg] = *(const short8*)&Wl[src];
    }
#pragma unroll
    for (int it = 0; it < 2; ++it) {
      int lin = tid + it * 256;
      int nn = lin >> 2, sg = (lin & 3) * 8;
      *(short8*)&Xb[nn][sg] =
          *(const short8*)&Xt[((size_t)b * 2048 + n0 + nn) * 256 + c0 + sg];
    }
    __syncthreads();

    short8 ah[4], al[4], bx[4];
#pragma unroll
    for (int ot = 0; ot < 4; ++ot) {
      ah[ot] = *(const short8*)&Wa[0][wo + 16 * ot + l15][8 * quad];
      al[ot] = *(const short8*)&Wa[1][wo + 16 * ot + l15][8 * quad];
    }
#pragma unroll
    for (int nt = 0; nt < 4; ++nt)
      bx[nt] = *(const short8*)&Xb[wn + 16 * nt + l15][8 * quad];
#pragma unroll
    for (int ot = 0; ot < 4; ++ot)
#pragma unroll
      for (int nt = 0; nt < 4; ++nt) {
        acc[ot][nt] =
            __builtin_amdgcn_mfma_f32_16x16x32_bf16(al[ot], bx[nt], acc[ot][nt], 0, 0, 0);
        acc[ot][nt] =
            __builtin_amdgcn_mfma_f32_16x16x32_bf16(ah[ot], bx[nt], acc[ot][nt], 0, 0, 0);
      }
  }

  if (isq) {
#pragma unroll
    for (int nt = 0; nt < 4; ++nt) {
      int n = n0 + wn + 16 * nt + l15;
      size_t base = ((size_t)b * 2048 + n) * 512;
#pragma unroll
      for (int ot = 0; ot < 4; ++ot) {
        int o = o0 + wo + 16 * ot + 4 * quad;
        short4v pk;
#pragma unroll
        for (int r = 0; r < 4; ++r) pk[r] = bf16r(CQ_ * acc[ot][nt][r]);
        *(short4v*)&qb[base + o] = pk;
      }
    }
  } else if (o0 < 512) {
    // K part: one head per wave (64 ch) x one 64-m chunk; -2*CQ scale.
    // Stage swizzled tile in LDS, then 8 coalesced 1KB stores.
    const int head = (o0 + wo) >> 6;
    const int bh = b * 8 + head;
    const int chunk = (n0 + wn) >> 6;
    __syncthreads();  // all waves done reading Wa/Xb; reuse as slabs
    short (*kt)[72] = (short (*)[72])(smem + w * 9216);
    float k2p[4] = {0.f, 0.f, 0.f, 0.f};
#pragma unroll
    for (int nt = 0; nt < 4; ++nt) {
      int mrow = 16 * nt + l15;
      int sw = mrow & 7;
#pragma unroll
      for (int ot = 0; ot < 4; ++ot) {
        int d0 = 16 * ot + 4 * quad;
        short4v pk;
#pragma unroll
        for (int r = 0; r < 4; ++r) {
          short pv = bf16r(NEG2CQ_ * acc[ot][nt][r]);
          pk[r] = pv;
          float kr = bf2f(pv);
          k2p[nt] += kr * kr;
        }
        *(short4v*)&kt[mrow][(((d0 >> 3) ^ sw) << 3) + (d0 & 7)] = pk;
      }
    }
    size_t tbase = ((size_t)bh * 32 + chunk) * 4096;
#pragma unroll
    for (int it = 0; it < 8; ++it) {
      int mr = 8 * it + (l >> 3);
      int c8 = (l & 7) * 8;
      *(short8*)&kc[tbase + mr * 64 + c8] = *(const short8*)&kt[mr][c8];
    }
#pragma unroll
    for (int nt = 0; nt < 4; ++nt) {
      float s = k2p[nt];
      s += __shfl_xor(s, 16);
      s += __shfl_xor(s, 32);
      if (quad == 0) {
        int m = n0 + wn + 16 * nt + l15;
        int mv = maskp[b * 2048 + m];
        k2m[(size_t)bh * 2048 + m] = mv ? 0.25f * s : __builtin_inff();
      }
    }
  } else {
    // V part: f16, column permute (PV A-frag order) + group swizzle.
    // Stage permuted tile in LDS, then 8 coalesced 1KB stores.
    const int chv = o0 - 512 + wo;  // head*64
    const int bh = b * 8 + (chv >> 6);
    const int chunk = (n0 + wn) >> 6;
    __syncthreads();  // all waves done reading Wa/Xb; reuse as slabs
    _Float16 (*vt)[72] = (_Float16 (*)[72])(smem + w * 9216);
#pragma unroll
    for (int nt = 0; nt < 4; ++nt) {
      int jr = 16 * nt + l15;
      int jrem = jr & 31;
      int colp = 32 * (jr >> 5) + ((jrem >> 2) & 3) * 8 + (jrem >> 4) * 4 +
                 (jrem & 3);
#pragma unroll
      for (int ot = 0; ot < 4; ++ot)
#pragma unroll
        for (int r = 0; r < 4; ++r) {
          int drow = (16 * ot + 4 * quad + r) & 63;
          vt[drow][(((colp >> 3) ^ (drow & 7)) << 3) + (colp & 7)] =
              (_Float16)acc[ot][nt][r];
        }
    }
    size_t cbase = ((size_t)bh * 32 + chunk) * 4096;
#pragma unroll
    for (int it = 0; it < 8; ++it) {
      int dr = 8 * it + (l >> 3);
      int c8 = (l & 7) * 8;
      *(half8*)&vc[cbase + dr * 64 + c8] = *(const half8*)&vt[dr][c8];
    }
  }
}

// ---------------------------------------------------------------------------
// Kernel 3: L2-distance flash attention (exact R3 body -- FROZEN).
// 8 waves / 512 threads per block: wave (wr,jh) = (w>>1, w&1); wr picks the
// 16 q-rows, jh picks the j-half (32 of 64) of each chunk. 8 waves/SIMD at
// 32KB LDS (4 blocks/CU). |C2| pre-folded into q/k/k2m, so inner loop is
// exp2(-sqrt(max(a,eps))). PV is ONE mfma_f32_16x16x32_f16 per dt.
// HISTORY: R2 (cross-chunk dbuf+pipeline) spilled -> 352us; R5 (lean
// pipeline) 76.6us; R6 (k2 prefetch) 81us. The simple form is fastest
// (69.9us); the compiler's schedule beats all source-level reorderings.
// ---------------------------------------------------------------------------
__global__ __launch_bounds__(512, 8) void attn_kernel(
    const short* __restrict__ qb, const short* __restrict__ kc,
    const _Float16* __restrict__ vc, const float* __restrict__ k2m,
    short* __restrict__ attn_t) {
  const int bid = blockIdx.x;
  const int rr = bid & 7, qq = bid >> 3;  // rr ~ XCD
  const int bh = rr * 4 + (qq >> 5);      // 4 bh per XCD
  const int iblk = qq & 31;
  const int h = bh & 7, b = bh >> 3;
  const int i0 = iblk * 64;

  const int tid = threadIdx.x;
  const int w = tid >> 6, l = tid & 63, quad = l >> 4, l15 = l & 15;
  const int wr = w >> 1, jh = w & 1;

  __shared__ __align__(16) short sbuf[2][2][4096];  // [K/V][dbuf][8KB]

  const short* qrow =
      qb + ((size_t)b * 2048 + i0 + 16 * wr + l15) * 512 + h * 64;
  const short* kcb = kc + (size_t)bh * 32 * 4096;
  const _Float16* vcb = vc + (size_t)bh * 32 * 4096;
  const float* k2b = k2m + (size_t)bh * 2048;

  // Q^T B-fragments (n=i=l15, k=d=8*quad+jj) + q2 (per-lane scalar, CQ^2-scaled)
  short8 qa0 = *(const short8*)&qrow[8 * quad];
  short8 qa1 = *(const short8*)&qrow[32 + 8 * quad];
  float q2p = 0.f;
#pragma unroll
  for (int jj = 0; jj < 8; ++jj) {
    float f0 = bf2f(qa0[jj]), f1 = bf2f(qa1[jj]);
    q2p += f0 * f0 + f1 * f1;
  }
  q2p += __shfl_xor(q2p, 16);
  q2p += __shfl_xor(q2p, 32);
  const float q2c = q2p;

  floatx4 accO[4];
#pragma unroll
  for (int dt = 0; dt < 4; ++dt)
#pragma unroll
    for (int r = 0; r < 4; ++r) accO[dt][r] = 0.f;
  float lsum = 0.f;

  const int sx = l15 & 7;  // swizzle key

  auto stage = [&](int c, int p) {
    const short* ks = kcb + (size_t)c * 4096 + w * 512 + l * 8;
    const _Float16* vs = vcb + (size_t)c * 4096 + w * 512 + l * 8;
#ifdef HAS_DMA
    __builtin_amdgcn_global_load_lds((gvoid_t*)ks,
                                     (lvoid_t*)&sbuf[0][p][w * 512], 16, 0, 0);
    __builtin_amdgcn_global_load_lds((gvoid_t*)vs,
                                     (lvoid_t*)&sbuf[1][p][w * 512], 16, 0, 0);
#else
    *(short8*)&sbuf[0][p][w * 512 + l * 8] = *(const short8*)ks;
    *(half8*)&((_Float16*)sbuf[1][p])[w * 512 + l * 8] = *(const half8*)vs;
#endif
  };

  stage(0, 0);
  for (int c = 0; c < 32; ++c) {
    __syncthreads();  // drains chunk-c DMA (vmcnt(0) before barrier)
    if (c < 31) stage(c + 1, (c + 1) & 1);
    const int p = c & 1;

    half8 pb;
#pragma unroll
    for (int jt = 0; jt < 2; ++jt) {
      float4 k2v = *(const float4*)&k2b[c * 64 + jh * 32 + 16 * jt + 4 * quad];
      const short* kr = &sbuf[0][p][(jh * 32 + 16 * jt + l15) * 64];
      short8 k0 = *(const short8*)&kr[(quad ^ sx) << 3];
      short8 k1 = *(const short8*)&kr[((quad + 4) ^ sx) << 3];
      floatx4 a;  // accumulator pre-loaded with q2 + k2 (both CQ^2-scaled)
      a[0] = q2c + k2v.x;
      a[1] = q2c + k2v.y;
      a[2] = q2c + k2v.z;
      a[3] = q2c + k2v.w;
      __builtin_amdgcn_s_setprio(1);
      a = __builtin_amdgcn_mfma_f32_16x16x32_bf16(k0, qa0, a, 0, 0, 0);
      a = __builtin_amdgcn_mfma_f32_16x16x32_bf16(k1, qa1, a, 0, 0, 0);
      __builtin_amdgcn_s_setprio(0);
#pragma unroll
      for (int r = 0; r < 4; ++r) {
        float s = __builtin_amdgcn_sqrtf(fmaxf(a[r], EPS2_));
        float pv = __builtin_amdgcn_exp2f(-s);  // neg is a free input modifier
        lsum += pv;
        pb[4 * jt + r] = (_Float16)pv;
      }
    }

    __builtin_amdgcn_s_setprio(1);
#pragma unroll
    for (int dt = 0; dt < 4; ++dt) {
      const _Float16* vr = (const _Float16*)&sbuf[1][p][(16 * dt + l15) * 64];
      half8 hh = *(const half8*)&vr[((quad + 4 * jh) ^ sx) << 3];
      accO[dt] =
          __builtin_amdgcn_mfma_f32_16x16x32_f16(hh, pb, accO[dt], 0, 0, 0);
    }
    __builtin_amdgcn_s_setprio(0);
  }

  // Merge jh=1 partials into jh=0 through LDS (buffers are dead now).
  __syncthreads();
  float* scr = (float*)sbuf;  // 4 waves * 64 lanes * 17 floats = 17408B < 32KB
  const int sidx = (wr * 64 + l) * 17;
  if (jh) {
#pragma unroll
    for (int dt = 0; dt < 4; ++dt)
#pragma unroll
      for (int r = 0; r < 4; ++r) scr[sidx + dt * 4 + r] = accO[dt][r];
    scr[sidx + 16] = lsum;
  }
  __syncthreads();
  if (!jh) {
#pragma unroll
    for (int dt = 0; dt < 4; ++dt)
#pragma unroll
      for (int r = 0; r < 4; ++r) accO[dt][r] += scr[sidx + dt * 4 + r];
    lsum += scr[sidx + 16];
    lsum += __shfl_xor(lsum, 16);
    lsum += __shfl_xor(lsum, 32);
    float rl = 1.0f / lsum;
    size_t base = ((size_t)b * 2048 + i0 + 16 * wr + l15) * 512 + h * 64;
#pragma unroll
    for (int dt = 0; dt < 4; ++dt) {
      short4v pk;
#pragma unroll
      for (int r = 0; r < 4; ++r) pk[r] = bf16r(accO[dt][r] * rl);
      *(short4v*)&attn_t[base + 16 * dt + 4 * quad] = pk;
    }
  }
}

// ---------------------------------------------------------------------------
// Kernel 4: out-projection MFMA GEMM, 64o x 128n tiles (256 blocks = 1/CU).
// Y fp32 [b][256][2048] = sum_c W'[o][c] * attn_t[b][n][c], C=512.
// 4 waves as 2x2: wave tile 32o x 64n, acc[2][4].
// ---------------------------------------------------------------------------
__global__ __launch_bounds__(256) void outproj_kernel(
    const short* __restrict__ whi, const short* __restrict__ wlo,
    const short* __restrict__ Xt, float* __restrict__ Yf) {
  const int b = blockIdx.z;
  const int n0 = blockIdx.x * 128;
  const int o0 = blockIdx.y * 64;
  const int tid = threadIdx.x;
  const int w = tid >> 6, l = tid & 63, quad = l >> 4, l15 = l & 15;
  const int wo = (w >> 1) * 32, wn = (w & 1) * 64;

  __shared__ __align__(16) short Wa[2][64][40];
  __shared__ __align__(16) short Xb[128][40];

  floatx4 acc[2][4];
#pragma unroll
  for (int ot = 0; ot < 2; ++ot)
#pragma unroll
    for (int nt = 0; nt < 4; ++nt)
#pragma unroll
      for (int r = 0; r < 4; ++r) acc[ot][nt][r] = 0.f;

  for (int c0 = 0; c0 < 512; c0 += 32) {
    __syncthreads();
    {
      int row = tid >> 2, sg = (tid & 3) * 8;  // 64 rows x 32c in one pass
      size_t src = (size_t)(o0 + row) * 512 + c0 + sg;
      *(short8*)&Wa[0][row][sg] = *(const short8*)&whi[src];
      *(short8*)&Wa[1][row][sg] = *(const short8*)&wlo[src];
    }
#pragma unroll
    for (int it = 0; it < 2; ++it) {
      int lin = tid + it * 256;
      int nn = lin >> 2, sg = (lin & 3) * 8;
      *(short8*)&Xb[nn][sg] =
          *(const short8*)&Xt[((size_t)b * 2048 + n0 + nn) * 512 + c0 + sg];
    }
    __syncthreads();

    short8 ah[2], al[2], bx[4];
#pragma unroll
    for (int ot = 0; ot < 2; ++ot) {
      ah[ot] = *(const short8*)&Wa[0][wo + 16 * ot + l15][8 * quad];
      al[ot] = *(const short8*)&Wa[1][wo + 16 * ot + l15][8 * quad];
    }
#pragma unroll
    for (int nt = 0; nt < 4; ++nt)
      bx[nt] = *(const short8*)&Xb[wn + 16 * nt + l15][8 * quad];
#pragma unroll
    for (int ot = 0; ot < 2; ++ot)
#pragma unroll
      for (int nt = 0; nt < 4; ++nt) {
        acc[ot][nt] =
            __builtin_amdgcn_mfma_f32_16x16x32_bf16(al[ot], bx[nt], acc[ot][nt], 0, 0, 0);
        acc[ot][nt] =
            __builtin_amdgcn_mfma_f32_16x16x32_bf16(ah[ot], bx[nt], acc[ot][nt], 0, 0, 0);
      }
  }

#pragma unroll
  for (int ot = 0; ot < 2; ++ot)
#pragma unroll
    for (int r = 0; r < 4; ++r) {
      int o = o0 + wo + 16 * ot + 4 * quad + r;
#pragma unroll
      for (int nt = 0; nt < 4; ++nt)
        Yf[((size_t)b * 256 + o) * 2048 + n0 + wn + 16 * nt + l15] =
            acc[ot][nt][r];
    }
}

// ---------------------------------------------------------------------------
extern "C" void kernel_launch(void* const* d_in, const int* in_sizes, int n_in,
                              void* d_out, int out_size, void* d_ws,
                              size_t ws_size, hipStream_t stream) {
  const float* fmap = (const float*)d_in[0];
  const float* context = (const float*)d_in[1];
  const int* mask = (const int*)d_in[2];
  const float* gamma = (const float*)d_in[3];
  const float* gamma_ctx = (const float*)d_in[4];
  const float* Wq = (const float*)d_in[5];
  const float* Wkv = (const float*)d_in[6];
  const float* Wout = (const float*)d_in[7];
  float* out = (float*)d_out;

  char* ws = (char*)d_ws;
  short* fmap_t = (short*)ws;                 // 4 MB
  short* ctx_t = fmap_t + 2097152;            // 4 MB
  short* qb = ctx_t + 2097152;                // 8 MB
  short* kc = qb + 4194304;                   // 8 MB (-2CQ*K, swizzled tiles)
  _Float16* vc = (_Float16*)(kc + 4194304);   // 8 MB (f16, permuted tiles)
  short* attn_t = (short*)(vc + 4194304);     // 8 MB
  float* k2m = (float*)(attn_t + 4194304);    // 256 KB
  short* whi = (short*)(k2m + 65536);         // 1 MB
  short* wlo = whi + 524288;                  // 1 MB

  preproc_kernel<<<dim3(1024), 256, 0, stream>>>(
      Wq, Wkv, Wout, gamma, gamma_ctx, whi, wlo, fmap, context, fmap_t, ctx_t);
  qkv_gemm_kernel<<<dim3(16, 12, B_), 256, 0, stream>>>(
      whi, wlo, fmap_t, ctx_t, qb, kc, vc, mask, k2m);
  attn_kernel<<<dim3(1024), 512, 0, stream>>>(qb, kc, vc, k2m, attn_t);
  outproj_kernel<<<dim3(16, 4, B_), 256, 0, stream>>>(whi + 393216,
                                                      wlo + 393216, attn_t,
                                                      out);
}

// Round 9
// 184.727 us; speedup vs baseline: 1.1453x; 1.0588x over previous
//
#include <hip/hip_runtime.h>
#include <hip/hip_bf16.h>

// Problem constants
#define B_ 4
#define DIM_ 256
#define N_ 2048
#define M_ 2048
#define HEADS_ 8
#define DHEAD_ 64
#define DINNER_ 512

typedef __attribute__((ext_vector_type(8))) short short8;
typedef __attribute__((ext_vector_type(4))) short short4v;
typedef __attribute__((ext_vector_type(4))) float floatx4;
typedef __attribute__((ext_vector_type(4))) _Float16 half4;
typedef __attribute__((ext_vector_type(8))) _Float16 half8;

#if defined(__has_builtin)
#if __has_builtin(__builtin_amdgcn_global_load_lds)
#define HAS_DMA 1
#endif
#endif

typedef __attribute__((address_space(1))) const void gvoid_t;
typedef __attribute__((address_space(3))) void lvoid_t;

// |C2| = 0.125 * log2(e); folded into Q and K bf16 planes so attention's
// inner loop computes pv = exp2(-sqrt(d2')) with zero extra multiplies.
#define CQ_ 0.18033688011112042f
#define NEG2CQ_ (-0.36067376022224084f)
#define EPS2_ 3.25213893e-14f  // 1e-12 * CQ^2

__device__ inline short bf16r(float x) {  // RNE f32->bf16 (bit form)
  unsigned u = __float_as_uint(x);
  unsigned r = (u + 0x7fffu + ((u >> 16) & 1u)) >> 16;
  return (short)r;
}
__device__ inline float bf2f(short b) {
  return __uint_as_float(((unsigned)(unsigned short)b) << 16);
}

// ---------------------------------------------------------------------------
// Kernel 0 (fused preproc): bid<768 -> W split (whi/wlo bf16 planes of
// W*gamma); bid>=768 -> channel RMSNorm -> bf16 transposed for fmap+context.
// R8: colnorm global reads vectorized to float4/lane (G13 -- were 4B/lane).
// ---------------------------------------------------------------------------
__global__ __launch_bounds__(256) void preproc_kernel(
    const float* __restrict__ Wq, const float* __restrict__ Wkv,
    const float* __restrict__ Wout, const float* __restrict__ gamma,
    const float* __restrict__ gctx, short* __restrict__ whi,
    short* __restrict__ wlo, const float* __restrict__ xf,
    const float* __restrict__ xc, short* __restrict__ xtf,
    short* __restrict__ xtc) {
  const int bid = blockIdx.x;
  const int tid = threadIdx.x;

  __shared__ float4 red4[16][16];
  __shared__ float scl[64];
  __shared__ float t[64][65];

  if (bid < 768) {
    // ---- W split part ----
    const int y = bid >> 8;  // 0..2
    const int gsz[3] = {32768, 65536, 32768};  // float4 groups per matrix
    const int goff[3] = {0, 131072, 393216};   // element offset in planes
    int gidx = (bid & 255) * 256 + tid;
    if (gidx >= gsz[y]) return;
    const float* W = (y == 0) ? Wq : (y == 1) ? Wkv : Wout;
    const int cmask = (y == 2) ? 511 : 255;
    int e0 = gidx * 4;
    int c = e0 & cmask;
    float4 wv = *(const float4*)&W[e0];
    if (y < 2) {
      const float* g = (y == 0) ? gamma : gctx;
      float4 g4 = *(const float4*)&g[c];
      wv.x *= g4.x; wv.y *= g4.y; wv.z *= g4.z; wv.w *= g4.w;
    }
    float vv[4] = {wv.x, wv.y, wv.z, wv.w};
    short4v hi, lo;
#pragma unroll
    for (int e = 0; e < 4; ++e) {
      short hb = bf16r(vv[e]);
      hi[e] = hb;
      lo[e] = bf16r(vv[e] - bf2f(hb));
    }
    *(short4v*)&whi[goff[y] + e0] = hi;
    *(short4v*)&wlo[goff[y] + e0] = lo;
    return;
  }

  // ---- colnorm part (float4-vectorized loads) ----
  const int cid = bid - 768;              // 0..255
  const int NN = 2048;
  const int z = cid >> 7;                 // 0..1
  const int b = (cid >> 5) & 3;           // 0..3
  const int xblk = cid & 31;              // 0..31
  const float* x = (z == 0) ? xf : xc;
  short* xt = (z == 0) ? xtf : xtc;
  const int tx4 = tid & 15, tyc = tid >> 4;  // n-quad 0..15, channel 0..15
  const int n0 = xblk * 64;
  const float* xb = x + (size_t)b * 256 * NN;

  float4 ssq4 = {0.f, 0.f, 0.f, 0.f};
  for (int c = tyc; c < 256; c += 16) {
    float4 v = *(const float4*)&xb[(size_t)c * NN + n0 + tx4 * 4];
    ssq4.x += v.x * v.x; ssq4.y += v.y * v.y;
    ssq4.z += v.z * v.z; ssq4.w += v.w * v.w;
  }
  red4[tyc][tx4] = ssq4;
  __syncthreads();
  if (tid < 16) {
    float4 s = red4[0][tid];
#pragma unroll
    for (int g = 1; g < 16; ++g) {
      float4 v = red4[g][tid];
      s.x += v.x; s.y += v.y; s.z += v.z; s.w += v.w;
    }
    scl[tid * 4 + 0] = 16.0f / fmaxf(sqrtf(s.x), 1e-12f);
    scl[tid * 4 + 1] = 16.0f / fmaxf(sqrtf(s.y), 1e-12f);
    scl[tid * 4 + 2] = 16.0f / fmaxf(sqrtf(s.z), 1e-12f);
    scl[tid * 4 + 3] = 16.0f / fmaxf(sqrtf(s.w), 1e-12f);
  }
  const int row = tid >> 2, cg = tid & 3;
  for (int c0 = 0; c0 < 256; c0 += 64) {
    __syncthreads();
    for (int cc = tyc; cc < 64; cc += 16) {
      float4 v = *(const float4*)&xb[(size_t)(c0 + cc) * NN + n0 + tx4 * 4];
      t[cc][tx4 * 4 + 0] = v.x;
      t[cc][tx4 * 4 + 1] = v.y;
      t[cc][tx4 * 4 + 2] = v.z;
      t[cc][tx4 * 4 + 3] = v.w;
    }
    __syncthreads();
    float sc = scl[row];
    short8 o0v, o1v;
#pragma unroll
    for (int e = 0; e < 8; ++e) {
      o0v[e] = bf16r(t[cg * 16 + e][row] * sc);
      o1v[e] = bf16r(t[cg * 16 + 8 + e][row] * sc);
    }
    size_t base = ((size_t)b * NN + n0 + row) * 256 + c0 + cg * 16;
    *(short8*)&xt[base] = o0v;
    *(short8*)&xt[base + 8] = o1v;
  }
}

// ---------------------------------------------------------------------------
// Kernel 2: fused Q + KV projection MFMA GEMM (one launch).
// grid (16, 12, B): y<4 -> q-proj (o0=y*128, X=fmap_t, out=qb bf16 [b][n][512],
// scaled by CQ); y>=4 -> kv-proj (o0=(y-4)*128, X=ctx_t): o0<512 K-part
// (-2*CQ scale, swizzled tiles + fused k2m/mask -> k2m = CQ^2*k2), else V-part
// (f16 permuted+swizzled tiles). K/V epilogues stage tiles through LDS and
// store with 8 coalesced 1KB instructions (R7, +4.3us verified).
// ---------------------------------------------------------------------------
__global__ __launch_bounds__(256) void qkv_gemm_kernel(
    const short* __restrict__ whi, const short* __restrict__ wlo,
    const short* __restrict__ fmap_t, const short* __restrict__ ctx_t,
    short* __restrict__ qb, short* __restrict__ kc, _Float16* __restrict__ vc,
    const int* __restrict__ maskp, float* __restrict__ k2m) {
  const int b = blockIdx.z;
  const int y = blockIdx.y;
  const bool isq = (y < 4);
  const int o0 = (isq ? y : y - 4) * 128;
  const int n0 = blockIdx.x * 128;
  const short* Wh = whi + (isq ? 0 : 131072);
  const short* Wl = wlo + (isq ? 0 : 131072);
  const short* Xt = isq ? fmap_t : ctx_t;

  const int tid = threadIdx.x;
  const int w = tid >> 6, l = tid & 63, quad = l >> 4, l15 = l & 15;
  const int wo = (w >> 1) * 64, wn = (w & 1) * 64;

  // Union: main loop Wa[2][128][40] (20480B) + Xb[128][40] (10240B) = 30720B;
  // epilogue 4 wave slabs of [64][72] shorts (9216B each) = 36864B.
  __shared__ __align__(16) char smem[36864];
  short (*Wa)[128][40] = (short (*)[128][40])smem;
  short (*Xb)[40] = (short (*)[40])(smem + 20480);

  floatx4 acc[4][4];
#pragma unroll
  for (int ot = 0; ot < 4; ++ot)
#pragma unroll
    for (int nt = 0; nt < 4; ++nt)
#pragma unroll
      for (int r = 0; r < 4; ++r) acc[ot][nt][r] = 0.f;

  for (int c0 = 0; c0 < 256; c0 += 32) {
    __syncthreads();
#pragma unroll
    for (int it = 0; it < 2; ++it) {
      int lin = tid + it * 256;
      int row = lin >> 2, sg = (lin & 3) * 8;
      size_t src = (size_t)(o0 + row) * 256 + c0 + sg;
      *(short8*)&Wa[0][row][sg] = *(const short8*)&Wh[src];
      *(short8*)&Wa[1][row][sg] = *(const short8*)&Wl[src];
    }
#pragma unroll
    for (int it = 0; it < 2; ++it) {
      int lin = tid + it * 256;
      int nn = lin >> 2, sg = (lin & 3) * 8;
      *(short8*)&Xb[nn][sg] =
          *(const short8*)&Xt[((size_t)b * 2048 + n0 + nn) * 256 + c0 + sg];
    }
    __syncthreads();

    short8 ah[4], al[4], bx[4];
#pragma unroll
    for (int ot = 0; ot < 4; ++ot) {
      ah[ot] = *(const short8*)&Wa[0][wo + 16 * ot + l15][8 * quad];
      al[ot] = *(const short8*)&Wa[1][wo + 16 * ot + l15][8 * quad];
    }
#pragma unroll
    for (int nt = 0; nt < 4; ++nt)
      bx[nt] = *(const short8*)&Xb[wn + 16 * nt + l15][8 * quad];
#pragma unroll
    for (int ot = 0; ot < 4; ++ot)
#pragma unroll
      for (int nt = 0; nt < 4; ++nt) {
        acc[ot][nt] =
            __builtin_amdgcn_mfma_f32_16x16x32_bf16(al[ot], bx[nt], acc[ot][nt], 0, 0, 0);
        acc[ot][nt] =
            __builtin_amdgcn_mfma_f32_16x16x32_bf16(ah[ot], bx[nt], acc[ot][nt], 0, 0, 0);
      }
  }

  if (isq) {
#pragma unroll
    for (int nt = 0; nt < 4; ++nt) {
      int n = n0 + wn + 16 * nt + l15;
      size_t base = ((size_t)b * 2048 + n) * 512;
#pragma unroll
      for (int ot = 0; ot < 4; ++ot) {
        int o = o0 + wo + 16 * ot + 4 * quad;
        short4v pk;
#pragma unroll
        for (int r = 0; r < 4; ++r) pk[r] = bf16r(CQ_ * acc[ot][nt][r]);
        *(short4v*)&qb[base + o] = pk;
      }
    }
  } else if (o0 < 512) {
    // K part: one head per wave (64 ch) x one 64-m chunk; -2*CQ scale.
    // Stage swizzled tile in LDS, then 8 coalesced 1KB stores.
    const int head = (o0 + wo) >> 6;
    const int bh = b * 8 + head;
    const int chunk = (n0 + wn) >> 6;
    __syncthreads();  // all waves done reading Wa/Xb; reuse as slabs
    short (*kt)[72] = (short (*)[72])(smem + w * 9216);
    float k2p[4] = {0.f, 0.f, 0.f, 0.f};
#pragma unroll
    for (int nt = 0; nt < 4; ++nt) {
      int mrow = 16 * nt + l15;
      int sw = mrow & 7;
#pragma unroll
      for (int ot = 0; ot < 4; ++ot) {
        int d0 = 16 * ot + 4 * quad;
        short4v pk;
#pragma unroll
        for (int r = 0; r < 4; ++r) {
          short pv = bf16r(NEG2CQ_ * acc[ot][nt][r]);
          pk[r] = pv;
          float kr = bf2f(pv);
          k2p[nt] += kr * kr;
        }
        *(short4v*)&kt[mrow][(((d0 >> 3) ^ sw) << 3) + (d0 & 7)] = pk;
      }
    }
    size_t tbase = ((size_t)bh * 32 + chunk) * 4096;
#pragma unroll
    for (int it = 0; it < 8; ++it) {
      int mr = 8 * it + (l >> 3);
      int c8 = (l & 7) * 8;
      *(short8*)&kc[tbase + mr * 64 + c8] = *(const short8*)&kt[mr][c8];
    }
#pragma unroll
    for (int nt = 0; nt < 4; ++nt) {
      float s = k2p[nt];
      s += __shfl_xor(s, 16);
      s += __shfl_xor(s, 32);
      if (quad == 0) {
        int m = n0 + wn + 16 * nt + l15;
        int mv = maskp[b * 2048 + m];
        k2m[(size_t)bh * 2048 + m] = mv ? 0.25f * s : __builtin_inff();
      }
    }
  } else {
    // V part: f16, column permute (PV A-frag order) + group swizzle.
    // Stage permuted tile in LDS, then 8 coalesced 1KB stores.
    const int chv = o0 - 512 + wo;  // head*64
    const int bh = b * 8 + (chv >> 6);
    const int chunk = (n0 + wn) >> 6;
    __syncthreads();  // all waves done reading Wa/Xb; reuse as slabs
    _Float16 (*vt)[72] = (_Float16 (*)[72])(smem + w * 9216);
#pragma unroll
    for (int nt = 0; nt < 4; ++nt) {
      int jr = 16 * nt + l15;
      int jrem = jr & 31;
      int colp = 32 * (jr >> 5) + ((jrem >> 2) & 3) * 8 + (jrem >> 4) * 4 +
                 (jrem & 3);
#pragma unroll
      for (int ot = 0; ot < 4; ++ot)
#pragma unroll
        for (int r = 0; r < 4; ++r) {
          int drow = (16 * ot + 4 * quad + r) & 63;
          vt[drow][(((colp >> 3) ^ (drow & 7)) << 3) + (colp & 7)] =
              (_Float16)acc[ot][nt][r];
        }
    }
    size_t cbase = ((size_t)bh * 32 + chunk) * 4096;
#pragma unroll
    for (int it = 0; it < 8; ++it) {
      int dr = 8 * it + (l >> 3);
      int c8 = (l & 7) * 8;
      *(half8*)&vc[cbase + dr * 64 + c8] = *(const half8*)&vt[dr][c8];
    }
  }
}

// ---------------------------------------------------------------------------
// Kernel 3: L2-distance flash attention (exact R3 body -- FROZEN).
// 8 waves / 512 threads per block: wave (wr,jh) = (w>>1, w&1); wr picks the
// 16 q-rows, jh picks the j-half (32 of 64) of each chunk. 8 waves/SIMD at
// 32KB LDS (4 blocks/CU). |C2| pre-folded into q/k/k2m, so inner loop is
// exp2(-sqrt(max(a,eps))). PV is ONE mfma_f32_16x16x32_f16 per dt.
// HISTORY: R2 (cross-chunk dbuf+pipeline) spilled -> 352us; R5 (lean
// pipeline) 76.6us; R6 (k2 prefetch) 81us. The simple form is fastest
// (69.9us); the compiler's schedule beats all source-level reorderings.
// ---------------------------------------------------------------------------
__global__ __launch_bounds__(512, 8) void attn_kernel(
    const short* __restrict__ qb, const short* __restrict__ kc,
    const _Float16* __restrict__ vc, const float* __restrict__ k2m,
    short* __restrict__ attn_t) {
  const int bid = blockIdx.x;
  const int rr = bid & 7, qq = bid >> 3;  // rr ~ XCD
  const int bh = rr * 4 + (qq >> 5);      // 4 bh per XCD
  const int iblk = qq & 31;
  const int h = bh & 7, b = bh >> 3;
  const int i0 = iblk * 64;

  const int tid = threadIdx.x;
  const int w = tid >> 6, l = tid & 63, quad = l >> 4, l15 = l & 15;
  const int wr = w >> 1, jh = w & 1;

  __shared__ __align__(16) short sbuf[2][2][4096];  // [K/V][dbuf][8KB]

  const short* qrow =
      qb + ((size_t)b * 2048 + i0 + 16 * wr + l15) * 512 + h * 64;
  const short* kcb = kc + (size_t)bh * 32 * 4096;
  const _Float16* vcb = vc + (size_t)bh * 32 * 4096;
  const float* k2b = k2m + (size_t)bh * 2048;

  // Q^T B-fragments (n=i=l15, k=d=8*quad+jj) + q2 (per-lane scalar, CQ^2-scaled)
  short8 qa0 = *(const short8*)&qrow[8 * quad];
  short8 qa1 = *(const short8*)&qrow[32 + 8 * quad];
  float q2p = 0.f;
#pragma unroll
  for (int jj = 0; jj < 8; ++jj) {
    float f0 = bf2f(qa0[jj]), f1 = bf2f(qa1[jj]);
    q2p += f0 * f0 + f1 * f1;
  }
  q2p += __shfl_xor(q2p, 16);
  q2p += __shfl_xor(q2p, 32);
  const float q2c = q2p;

  floatx4 accO[4];
#pragma unroll
  for (int dt = 0; dt < 4; ++dt)
#pragma unroll
    for (int r = 0; r < 4; ++r) accO[dt][r] = 0.f;
  float lsum = 0.f;

  const int sx = l15 & 7;  // swizzle key

  auto stage = [&](int c, int p) {
    const short* ks = kcb + (size_t)c * 4096 + w * 512 + l * 8;
    const _Float16* vs = vcb + (size_t)c * 4096 + w * 512 + l * 8;
#ifdef HAS_DMA
    __builtin_amdgcn_global_load_lds((gvoid_t*)ks,
                                     (lvoid_t*)&sbuf[0][p][w * 512], 16, 0, 0);
    __builtin_amdgcn_global_load_lds((gvoid_t*)vs,
                                     (lvoid_t*)&sbuf[1][p][w * 512], 16, 0, 0);
#else
    *(short8*)&sbuf[0][p][w * 512 + l * 8] = *(const short8*)ks;
    *(half8*)&((_Float16*)sbuf[1][p])[w * 512 + l * 8] = *(const half8*)vs;
#endif
  };

  stage(0, 0);
  for (int c = 0; c < 32; ++c) {
    __syncthreads();  // drains chunk-c DMA (vmcnt(0) before barrier)
    if (c < 31) stage(c + 1, (c + 1) & 1);
    const int p = c & 1;

    half8 pb;
#pragma unroll
    for (int jt = 0; jt < 2; ++jt) {
      float4 k2v = *(const float4*)&k2b[c * 64 + jh * 32 + 16 * jt + 4 * quad];
      const short* kr = &sbuf[0][p][(jh * 32 + 16 * jt + l15) * 64];
      short8 k0 = *(const short8*)&kr[(quad ^ sx) << 3];
      short8 k1 = *(const short8*)&kr[((quad + 4) ^ sx) << 3];
      floatx4 a;  // accumulator pre-loaded with q2 + k2 (both CQ^2-scaled)
      a[0] = q2c + k2v.x;
      a[1] = q2c + k2v.y;
      a[2] = q2c + k2v.z;
      a[3] = q2c + k2v.w;
      __builtin_amdgcn_s_setprio(1);
      a = __builtin_amdgcn_mfma_f32_16x16x32_bf16(k0, qa0, a, 0, 0, 0);
      a = __builtin_amdgcn_mfma_f32_16x16x32_bf16(k1, qa1, a, 0, 0, 0);
      __builtin_amdgcn_s_setprio(0);
#pragma unroll
      for (int r = 0; r < 4; ++r) {
        float s = __builtin_amdgcn_sqrtf(fmaxf(a[r], EPS2_));
        float pv = __builtin_amdgcn_exp2f(-s);  // neg is a free input modifier
        lsum += pv;
        pb[4 * jt + r] = (_Float16)pv;
      }
    }

    __builtin_amdgcn_s_setprio(1);
#pragma unroll
    for (int dt = 0; dt < 4; ++dt) {
      const _Float16* vr = (const _Float16*)&sbuf[1][p][(16 * dt + l15) * 64];
      half8 hh = *(const half8*)&vr[((quad + 4 * jh) ^ sx) << 3];
      accO[dt] =
          __builtin_amdgcn_mfma_f32_16x16x32_f16(hh, pb, accO[dt], 0, 0, 0);
    }
    __builtin_amdgcn_s_setprio(0);
  }

  // Merge jh=1 partials into jh=0 through LDS (buffers are dead now).
  __syncthreads();
  float* scr = (float*)sbuf;  // 4 waves * 64 lanes * 17 floats = 17408B < 32KB
  const int sidx = (wr * 64 + l) * 17;
  if (jh) {
#pragma unroll
    for (int dt = 0; dt < 4; ++dt)
#pragma unroll
      for (int r = 0; r < 4; ++r) scr[sidx + dt * 4 + r] = accO[dt][r];
    scr[sidx + 16] = lsum;
  }
  __syncthreads();
  if (!jh) {
#pragma unroll
    for (int dt = 0; dt < 4; ++dt)
#pragma unroll
      for (int r = 0; r < 4; ++r) accO[dt][r] += scr[sidx + dt * 4 + r];
    lsum += scr[sidx + 16];
    lsum += __shfl_xor(lsum, 16);
    lsum += __shfl_xor(lsum, 32);
    float rl = 1.0f / lsum;
    size_t base = ((size_t)b * 2048 + i0 + 16 * wr + l15) * 512 + h * 64;
#pragma unroll
    for (int dt = 0; dt < 4; ++dt) {
      short4v pk;
#pragma unroll
      for (int r = 0; r < 4; ++r) pk[r] = bf16r(accO[dt][r] * rl);
      *(short4v*)&attn_t[base + 16 * dt + 4 * quad] = pk;
    }
  }
}

// ---------------------------------------------------------------------------
// Kernel 4: out-projection MFMA GEMM.
// R8: 64o x 64n tiles, grid (32,4,B) = 512 blocks = 2 blocks/CU (was 256 =
// 1/CU = 1 wave/SIMD -- latency-bound, nothing to hide the 16 K-iterations'
// barrier+staging latency). 4 waves as 2x2: wave tile 32o x 32n, acc[2][2].
// LDS 15.4KB.
// ---------------------------------------------------------------------------
__global__ __launch_bounds__(256) void outproj_kernel(
    const short* __restrict__ whi, const short* __restrict__ wlo,
    const short* __restrict__ Xt, float* __restrict__ Yf) {
  const int b = blockIdx.z;
  const int n0 = blockIdx.x * 64;
  const int o0 = blockIdx.y * 64;
  const int tid = threadIdx.x;
  const int w = tid >> 6, l = tid & 63, quad = l >> 4, l15 = l & 15;
  const int wo = (w >> 1) * 32, wn = (w & 1) * 32;

  __shared__ __align__(16) short Wa[2][64][40];
  __shared__ __align__(16) short Xb[64][40];

  floatx4 acc[2][2];
#pragma unroll
  for (int ot = 0; ot < 2; ++ot)
#pragma unroll
    for (int nt = 0; nt < 2; ++nt)
#pragma unroll
      for (int r = 0; r < 4; ++r) acc[ot][nt][r] = 0.f;

  for (int c0 = 0; c0 < 512; c0 += 32) {
    __syncthreads();
    {
      int row = tid >> 2, sg = (tid & 3) * 8;  // 64 rows x 32c in one pass
      size_t src = (size_t)(o0 + row) * 512 + c0 + sg;
      *(short8*)&Wa[0][row][sg] = *(const short8*)&whi[src];
      *(short8*)&Wa[1][row][sg] = *(const short8*)&wlo[src];
    }
    {
      int nn = tid >> 2, sg = (tid & 3) * 8;  // 64 rows x 32c in one pass
      *(short8*)&Xb[nn][sg] =
          *(const short8*)&Xt[((size_t)b * 2048 + n0 + nn) * 512 + c0 + sg];
    }
    __syncthreads();

    short8 ah[2], al[2], bx[2];
#pragma unroll
    for (int ot = 0; ot < 2; ++ot) {
      ah[ot] = *(const short8*)&Wa[0][wo + 16 * ot + l15][8 * quad];
      al[ot] = *(const short8*)&Wa[1][wo + 16 * ot + l15][8 * quad];
    }
#pragma unroll
    for (int nt = 0; nt < 2; ++nt)
      bx[nt] = *(const short8*)&Xb[wn + 16 * nt + l15][8 * quad];
#pragma unroll
    for (int ot = 0; ot < 2; ++ot)
#pragma unroll
      for (int nt = 0; nt < 2; ++nt) {
        acc[ot][nt] =
            __builtin_amdgcn_mfma_f32_16x16x32_bf16(al[ot], bx[nt], acc[ot][nt], 0, 0, 0);
        acc[ot][nt] =
            __builtin_amdgcn_mfma_f32_16x16x32_bf16(ah[ot], bx[nt], acc[ot][nt], 0, 0, 0);
      }
  }

#pragma unroll
  for (int ot = 0; ot < 2; ++ot)
#pragma unroll
    for (int r = 0; r < 4; ++r) {
      int o = o0 + wo + 16 * ot + 4 * quad + r;
#pragma unroll
      for (int nt = 0; nt < 2; ++nt)
        Yf[((size_t)b * 256 + o) * 2048 + n0 + wn + 16 * nt + l15] =
            acc[ot][nt][r];
    }
}

// ---------------------------------------------------------------------------
extern "C" void kernel_launch(void* const* d_in, const int* in_sizes, int n_in,
                              void* d_out, int out_size, void* d_ws,
                              size_t ws_size, hipStream_t stream) {
  const float* fmap = (const float*)d_in[0];
  const float* context = (const float*)d_in[1];
  const int* mask = (const int*)d_in[2];
  const float* gamma = (const float*)d_in[3];
  const float* gamma_ctx = (const float*)d_in[4];
  const float* Wq = (const float*)d_in[5];
  const float* Wkv = (const float*)d_in[6];
  const float* Wout = (const float*)d_in[7];
  float* out = (float*)d_out;

  char* ws = (char*)d_ws;
  short* fmap_t = (short*)ws;                 // 4 MB
  short* ctx_t = fmap_t + 2097152;            // 4 MB
  short* qb = ctx_t + 2097152;                // 8 MB
  short* kc = qb + 4194304;                   // 8 MB (-2CQ*K, swizzled tiles)
  _Float16* vc = (_Float16*)(kc + 4194304);   // 8 MB (f16, permuted tiles)
  short* attn_t = (short*)(vc + 4194304);     // 8 MB
  float* k2m = (float*)(attn_t + 4194304);    // 256 KB
  short* whi = (short*)(k2m + 65536);         // 1 MB
  short* wlo = whi + 524288;                  // 1 MB

  preproc_kernel<<<dim3(1024), 256, 0, stream>>>(
      Wq, Wkv, Wout, gamma, gamma_ctx, whi, wlo, fmap, context, fmap_t, ctx_t);
  qkv_gemm_kernel<<<dim3(16, 12, B_), 256, 0, stream>>>(
      whi, wlo, fmap_t, ctx_t, qb, kc, vc, mask, k2m);
  attn_kernel<<<dim3(1024), 512, 0, stream>>>(qb, kc, vc, k2m, attn_t);
  outproj_kernel<<<dim3(32, 4, B_), 256, 0, stream>>>(whi + 393216,
                                                      wlo + 393216, attn_t,
                                                      out);
}

// Round 10
// 181.950 us; speedup vs baseline: 1.1628x; 1.0153x over previous
//
#include <hip/hip_runtime.h>
#include <hip/hip_bf16.h>

// Problem constants
#define B_ 4
#define DIM_ 256
#define N_ 2048
#define M_ 2048
#define HEADS_ 8
#define DHEAD_ 64
#define DINNER_ 512

typedef __attribute__((ext_vector_type(8))) short short8;
typedef __attribute__((ext_vector_type(4))) short short4v;
typedef __attribute__((ext_vector_type(4))) float floatx4;
typedef __attribute__((ext_vector_type(4))) _Float16 half4;
typedef __attribute__((ext_vector_type(8))) _Float16 half8;

#if defined(__has_builtin)
#if __has_builtin(__builtin_amdgcn_global_load_lds)
#define HAS_DMA 1
#endif
#endif

typedef __attribute__((address_space(1))) const void gvoid_t;
typedef __attribute__((address_space(3))) void lvoid_t;

// |C2| = 0.125 * log2(e); folded into Q and K bf16 planes so attention's
// inner loop computes pv = exp2(-sqrt(d2')) with zero extra multiplies.
#define CQ_ 0.18033688011112042f
#define NEG2CQ_ (-0.36067376022224084f)
#define EPS2_ 3.25213893e-14f  // 1e-12 * CQ^2

__device__ inline short bf16r(float x) {  // RNE f32->bf16 (bit form)
  unsigned u = __float_as_uint(x);
  unsigned r = (u + 0x7fffu + ((u >> 16) & 1u)) >> 16;
  return (short)r;
}
__device__ inline float bf2f(short b) {
  return __uint_as_float(((unsigned)(unsigned short)b) << 16);
}

// ---------------------------------------------------------------------------
// Kernel 0 (fused preproc): bid<768 -> W split (whi/wlo bf16 planes of
// W*gamma); bid>=768 -> channel RMSNorm -> bf16 transposed for fmap+context.
// colnorm global reads float4-vectorized (R8, verified).
// ---------------------------------------------------------------------------
__global__ __launch_bounds__(256) void preproc_kernel(
    const float* __restrict__ Wq, const float* __restrict__ Wkv,
    const float* __restrict__ Wout, const float* __restrict__ gamma,
    const float* __restrict__ gctx, short* __restrict__ whi,
    short* __restrict__ wlo, const float* __restrict__ xf,
    const float* __restrict__ xc, short* __restrict__ xtf,
    short* __restrict__ xtc) {
  const int bid = blockIdx.x;
  const int tid = threadIdx.x;

  __shared__ float4 red4[16][16];
  __shared__ float scl[64];
  __shared__ float t[64][65];

  if (bid < 768) {
    // ---- W split part ----
    const int y = bid >> 8;  // 0..2
    const int gsz[3] = {32768, 65536, 32768};  // float4 groups per matrix
    const int goff[3] = {0, 131072, 393216};   // element offset in planes
    int gidx = (bid & 255) * 256 + tid;
    if (gidx >= gsz[y]) return;
    const float* W = (y == 0) ? Wq : (y == 1) ? Wkv : Wout;
    const int cmask = (y == 2) ? 511 : 255;
    int e0 = gidx * 4;
    int c = e0 & cmask;
    float4 wv = *(const float4*)&W[e0];
    if (y < 2) {
      const float* g = (y == 0) ? gamma : gctx;
      float4 g4 = *(const float4*)&g[c];
      wv.x *= g4.x; wv.y *= g4.y; wv.z *= g4.z; wv.w *= g4.w;
    }
    float vv[4] = {wv.x, wv.y, wv.z, wv.w};
    short4v hi, lo;
#pragma unroll
    for (int e = 0; e < 4; ++e) {
      short hb = bf16r(vv[e]);
      hi[e] = hb;
      lo[e] = bf16r(vv[e] - bf2f(hb));
    }
    *(short4v*)&whi[goff[y] + e0] = hi;
    *(short4v*)&wlo[goff[y] + e0] = lo;
    return;
  }

  // ---- colnorm part (float4-vectorized loads) ----
  const int cid = bid - 768;              // 0..255
  const int NN = 2048;
  const int z = cid >> 7;                 // 0..1
  const int b = (cid >> 5) & 3;           // 0..3
  const int xblk = cid & 31;              // 0..31
  const float* x = (z == 0) ? xf : xc;
  short* xt = (z == 0) ? xtf : xtc;
  const int tx4 = tid & 15, tyc = tid >> 4;  // n-quad 0..15, channel 0..15
  const int n0 = xblk * 64;
  const float* xb = x + (size_t)b * 256 * NN;

  float4 ssq4 = {0.f, 0.f, 0.f, 0.f};
  for (int c = tyc; c < 256; c += 16) {
    float4 v = *(const float4*)&xb[(size_t)c * NN + n0 + tx4 * 4];
    ssq4.x += v.x * v.x; ssq4.y += v.y * v.y;
    ssq4.z += v.z * v.z; ssq4.w += v.w * v.w;
  }
  red4[tyc][tx4] = ssq4;
  __syncthreads();
  if (tid < 16) {
    float4 s = red4[0][tid];
#pragma unroll
    for (int g = 1; g < 16; ++g) {
      float4 v = red4[g][tid];
      s.x += v.x; s.y += v.y; s.z += v.z; s.w += v.w;
    }
    scl[tid * 4 + 0] = 16.0f / fmaxf(sqrtf(s.x), 1e-12f);
    scl[tid * 4 + 1] = 16.0f / fmaxf(sqrtf(s.y), 1e-12f);
    scl[tid * 4 + 2] = 16.0f / fmaxf(sqrtf(s.z), 1e-12f);
    scl[tid * 4 + 3] = 16.0f / fmaxf(sqrtf(s.w), 1e-12f);
  }
  const int row = tid >> 2, cg = tid & 3;
  for (int c0 = 0; c0 < 256; c0 += 64) {
    __syncthreads();
    for (int cc = tyc; cc < 64; cc += 16) {
      float4 v = *(const float4*)&xb[(size_t)(c0 + cc) * NN + n0 + tx4 * 4];
      t[cc][tx4 * 4 + 0] = v.x;
      t[cc][tx4 * 4 + 1] = v.y;
      t[cc][tx4 * 4 + 2] = v.z;
      t[cc][tx4 * 4 + 3] = v.w;
    }
    __syncthreads();
    float sc = scl[row];
    short8 o0v, o1v;
#pragma unroll
    for (int e = 0; e < 8; ++e) {
      o0v[e] = bf16r(t[cg * 16 + e][row] * sc);
      o1v[e] = bf16r(t[cg * 16 + 8 + e][row] * sc);
    }
    size_t base = ((size_t)b * NN + n0 + row) * 256 + c0 + cg * 16;
    *(short8*)&xt[base] = o0v;
    *(short8*)&xt[base + 8] = o1v;
  }
}

// ---------------------------------------------------------------------------
// Kernel 2: fused Q + KV projection MFMA GEMM (one launch).
// grid (16, 12, B): y<4 -> q-proj; y>=4 -> kv-proj (K-part / V-part).
// R10: main-loop staging via global_load_lds DMA (rule #21: LINEAR LDS
// [128][32] dest + inverse-XOR-swizzled per-lane GLOBAL source + XOR-swizzled
// reads). Swizzle: LDS[row][slot] holds global chunk slot^((row>>1)&3);
// read slot = quad^((row>>1)&3). Within each quarter-wave the b128 reads are
// 2-way bank-aliased = free (m136). Q epilogue now LDS-staged like K/V
// (was 16x 8B scatter at 1KB stride). All values bit-identical to R9.
// LDS: 24KB main loop, 36.9KB epilogue slabs (union), 4 blocks/CU cap,
// grid gives 3/CU.
// ---------------------------------------------------------------------------
__global__ __launch_bounds__(256) void qkv_gemm_kernel(
    const short* __restrict__ whi, const short* __restrict__ wlo,
    const short* __restrict__ fmap_t, const short* __restrict__ ctx_t,
    short* __restrict__ qb, short* __restrict__ kc, _Float16* __restrict__ vc,
    const int* __restrict__ maskp, float* __restrict__ k2m) {
  const int b = blockIdx.z;
  const int y = blockIdx.y;
  const bool isq = (y < 4);
  const int o0 = (isq ? y : y - 4) * 128;
  const int n0 = blockIdx.x * 128;
  const short* Wh = whi + (isq ? 0 : 131072);
  const short* Wl = wlo + (isq ? 0 : 131072);
  const short* Xt = isq ? fmap_t : ctx_t;

  const int tid = threadIdx.x;
  const int w = tid >> 6, l = tid & 63, quad = l >> 4, l15 = l & 15;
  const int wo = (w >> 1) * 64, wn = (w & 1) * 64;

  // Main loop: lWh[128][32] + lWl[128][32] + lXb[128][32] = 24KB (linear,
  // DMA-compatible). Epilogue: 4 wave slabs of [64][72] shorts = 36864B.
  __shared__ __align__(16) char smem[36864];
  short* lWh = (short*)smem;
  short* lWl = (short*)(smem + 8192);
  short* lXb = (short*)(smem + 16384);

  floatx4 acc[4][4];
#pragma unroll
  for (int ot = 0; ot < 4; ++ot)
#pragma unroll
    for (int nt = 0; nt < 4; ++nt)
#pragma unroll
      for (int r = 0; r < 4; ++r) acc[ot][nt][r] = 0.f;

  const int drow = l >> 2;   // 0..15 within a 16-row DMA group
  const int dslot = l & 3;   // 16B slot within a 64B row

  for (int c0 = 0; c0 < 256; c0 += 32) {
    __syncthreads();  // WAR: prior iteration's ds_reads done
#pragma unroll
    for (int half = 0; half < 2; ++half) {
      int r0 = w * 32 + half * 16;
      int row = r0 + drow;
      int chunk = dslot ^ ((row >> 1) & 3);
      size_t wsrc = (size_t)(o0 + row) * 256 + c0 + chunk * 8;
      size_t xsrc = ((size_t)b * 2048 + n0 + row) * 256 + c0 + chunk * 8;
#ifdef HAS_DMA
      __builtin_amdgcn_global_load_lds((gvoid_t*)&Wh[wsrc],
                                       (lvoid_t*)&lWh[r0 * 32], 16, 0, 0);
      __builtin_amdgcn_global_load_lds((gvoid_t*)&Wl[wsrc],
                                       (lvoid_t*)&lWl[r0 * 32], 16, 0, 0);
      __builtin_amdgcn_global_load_lds((gvoid_t*)&Xt[xsrc],
                                       (lvoid_t*)&lXb[r0 * 32], 16, 0, 0);
#else
      *(short8*)&lWh[row * 32 + dslot * 8] = *(const short8*)&Wh[wsrc];
      *(short8*)&lWl[row * 32 + dslot * 8] = *(const short8*)&Wl[wsrc];
      *(short8*)&lXb[row * 32 + dslot * 8] = *(const short8*)&Xt[xsrc];
#endif
    }
    __syncthreads();  // drains DMA (vmcnt(0) before barrier)

    short8 ah[4], al[4], bx[4];
#pragma unroll
    for (int ot = 0; ot < 4; ++ot) {
      int ar = wo + 16 * ot + l15;
      int sl = (quad ^ ((ar >> 1) & 3)) * 8;
      ah[ot] = *(const short8*)&lWh[ar * 32 + sl];
      al[ot] = *(const short8*)&lWl[ar * 32 + sl];
    }
#pragma unroll
    for (int nt = 0; nt < 4; ++nt) {
      int br = wn + 16 * nt + l15;
      int sl = (quad ^ ((br >> 1) & 3)) * 8;
      bx[nt] = *(const short8*)&lXb[br * 32 + sl];
    }
#pragma unroll
    for (int ot = 0; ot < 4; ++ot)
#pragma unroll
      for (int nt = 0; nt < 4; ++nt) {
        acc[ot][nt] =
            __builtin_amdgcn_mfma_f32_16x16x32_bf16(al[ot], bx[nt], acc[ot][nt], 0, 0, 0);
        acc[ot][nt] =
            __builtin_amdgcn_mfma_f32_16x16x32_bf16(ah[ot], bx[nt], acc[ot][nt], 0, 0, 0);
      }
  }

  if (isq) {
    // Q epilogue: LDS-stage the wave's 64x64 tile ([n][o]), then 8 coalesced
    // 128B row-pieces per wave (was 16x 8B scatter at 1KB stride).
    __syncthreads();  // all waves done reading lWh/lWl/lXb; reuse as slabs
    short (*qt)[72] = (short (*)[72])(smem + w * 9216);
#pragma unroll
    for (int nt = 0; nt < 4; ++nt)
#pragma unroll
      for (int ot = 0; ot < 4; ++ot) {
        short4v pk;
#pragma unroll
        for (int r = 0; r < 4; ++r) pk[r] = bf16r(CQ_ * acc[ot][nt][r]);
        *(short4v*)&qt[16 * nt + l15][16 * ot + 4 * quad] = pk;
      }
#pragma unroll
    for (int it = 0; it < 8; ++it) {
      int nr = 8 * it + (l >> 3);
      int c8 = (l & 7) * 8;
      *(short8*)&qb[((size_t)b * 2048 + n0 + wn + nr) * 512 + o0 + wo + c8] =
          *(const short8*)&qt[nr][c8];
    }
  } else if (o0 < 512) {
    // K part: one head per wave (64 ch) x one 64-m chunk; -2*CQ scale.
    // Stage swizzled tile in LDS, then 8 coalesced 1KB stores.
    const int head = (o0 + wo) >> 6;
    const int bh = b * 8 + head;
    const int chunk = (n0 + wn) >> 6;
    __syncthreads();  // all waves done reading main-loop tiles; reuse as slabs
    short (*kt)[72] = (short (*)[72])(smem + w * 9216);
    float k2p[4] = {0.f, 0.f, 0.f, 0.f};
#pragma unroll
    for (int nt = 0; nt < 4; ++nt) {
      int mrow = 16 * nt + l15;
      int sw = mrow & 7;
#pragma unroll
      for (int ot = 0; ot < 4; ++ot) {
        int d0 = 16 * ot + 4 * quad;
        short4v pk;
#pragma unroll
        for (int r = 0; r < 4; ++r) {
          short pv = bf16r(NEG2CQ_ * acc[ot][nt][r]);
          pk[r] = pv;
          float kr = bf2f(pv);
          k2p[nt] += kr * kr;
        }
        *(short4v*)&kt[mrow][(((d0 >> 3) ^ sw) << 3) + (d0 & 7)] = pk;
      }
    }
    size_t tbase = ((size_t)bh * 32 + chunk) * 4096;
#pragma unroll
    for (int it = 0; it < 8; ++it) {
      int mr = 8 * it + (l >> 3);
      int c8 = (l & 7) * 8;
      *(short8*)&kc[tbase + mr * 64 + c8] = *(const short8*)&kt[mr][c8];
    }
#pragma unroll
    for (int nt = 0; nt < 4; ++nt) {
      float s = k2p[nt];
      s += __shfl_xor(s, 16);
      s += __shfl_xor(s, 32);
      if (quad == 0) {
        int m = n0 + wn + 16 * nt + l15;
        int mv = maskp[b * 2048 + m];
        k2m[(size_t)bh * 2048 + m] = mv ? 0.25f * s : __builtin_inff();
      }
    }
  } else {
    // V part: f16, column permute (PV A-frag order) + group swizzle.
    // Stage permuted tile in LDS, then 8 coalesced 1KB stores.
    const int chv = o0 - 512 + wo;  // head*64
    const int bh = b * 8 + (chv >> 6);
    const int chunk = (n0 + wn) >> 6;
    __syncthreads();  // all waves done reading main-loop tiles; reuse as slabs
    _Float16 (*vt)[72] = (_Float16 (*)[72])(smem + w * 9216);
#pragma unroll
    for (int nt = 0; nt < 4; ++nt) {
      int jr = 16 * nt + l15;
      int jrem = jr & 31;
      int colp = 32 * (jr >> 5) + ((jrem >> 2) & 3) * 8 + (jrem >> 4) * 4 +
                 (jrem & 3);
#pragma unroll
      for (int ot = 0; ot < 4; ++ot)
#pragma unroll
        for (int r = 0; r < 4; ++r) {
          int drw = (16 * ot + 4 * quad + r) & 63;
          vt[drw][(((colp >> 3) ^ (drw & 7)) << 3) + (colp & 7)] =
              (_Float16)acc[ot][nt][r];
        }
    }
    size_t cbase = ((size_t)bh * 32 + chunk) * 4096;
#pragma unroll
    for (int it = 0; it < 8; ++it) {
      int dr = 8 * it + (l >> 3);
      int c8 = (l & 7) * 8;
      *(half8*)&vc[cbase + dr * 64 + c8] = *(const half8*)&vt[dr][c8];
    }
  }
}

// ---------------------------------------------------------------------------
// Kernel 3: L2-distance flash attention (exact R3 body -- FROZEN).
// 8 waves / 512 threads per block: wave (wr,jh) = (w>>1, w&1); wr picks the
// 16 q-rows, jh picks the j-half (32 of 64) of each chunk. 8 waves/SIMD at
// 32KB LDS (4 blocks/CU). |C2| pre-folded into q/k/k2m, so inner loop is
// exp2(-sqrt(max(a,eps))). PV is ONE mfma_f32_16x16x32_f16 per dt.
// HISTORY: R2 (cross-chunk dbuf+pipeline) spilled -> 352us; R5 (lean
// pipeline) 76.6us; R6 (k2 prefetch) 81us. The simple form is fastest
// (69.9us); the compiler's schedule beats all source-level reorderings.
// ---------------------------------------------------------------------------
__global__ __launch_bounds__(512, 8) void attn_kernel(
    const short* __restrict__ qb, const short* __restrict__ kc,
    const _Float16* __restrict__ vc, const float* __restrict__ k2m,
    short* __restrict__ attn_t) {
  const int bid = blockIdx.x;
  const int rr = bid & 7, qq = bid >> 3;  // rr ~ XCD
  const int bh = rr * 4 + (qq >> 5);      // 4 bh per XCD
  const int iblk = qq & 31;
  const int h = bh & 7, b = bh >> 3;
  const int i0 = iblk * 64;

  const int tid = threadIdx.x;
  const int w = tid >> 6, l = tid & 63, quad = l >> 4, l15 = l & 15;
  const int wr = w >> 1, jh = w & 1;

  __shared__ __align__(16) short sbuf[2][2][4096];  // [K/V][dbuf][8KB]

  const short* qrow =
      qb + ((size_t)b * 2048 + i0 + 16 * wr + l15) * 512 + h * 64;
  const short* kcb = kc + (size_t)bh * 32 * 4096;
  const _Float16* vcb = vc + (size_t)bh * 32 * 4096;
  const float* k2b = k2m + (size_t)bh * 2048;

  // Q^T B-fragments (n=i=l15, k=d=8*quad+jj) + q2 (per-lane scalar, CQ^2-scaled)
  short8 qa0 = *(const short8*)&qrow[8 * quad];
  short8 qa1 = *(const short8*)&qrow[32 + 8 * quad];
  float q2p = 0.f;
#pragma unroll
  for (int jj = 0; jj < 8; ++jj) {
    float f0 = bf2f(qa0[jj]), f1 = bf2f(qa1[jj]);
    q2p += f0 * f0 + f1 * f1;
  }
  q2p += __shfl_xor(q2p, 16);
  q2p += __shfl_xor(q2p, 32);
  const float q2c = q2p;

  floatx4 accO[4];
#pragma unroll
  for (int dt = 0; dt < 4; ++dt)
#pragma unroll
    for (int r = 0; r < 4; ++r) accO[dt][r] = 0.f;
  float lsum = 0.f;

  const int sx = l15 & 7;  // swizzle key

  auto stage = [&](int c, int p) {
    const short* ks = kcb + (size_t)c * 4096 + w * 512 + l * 8;
    const _Float16* vs = vcb + (size_t)c * 4096 + w * 512 + l * 8;
#ifdef HAS_DMA
    __builtin_amdgcn_global_load_lds((gvoid_t*)ks,
                                     (lvoid_t*)&sbuf[0][p][w * 512], 16, 0, 0);
    __builtin_amdgcn_global_load_lds((gvoid_t*)vs,
                                     (lvoid_t*)&sbuf[1][p][w * 512], 16, 0, 0);
#else
    *(short8*)&sbuf[0][p][w * 512 + l * 8] = *(const short8*)ks;
    *(half8*)&((_Float16*)sbuf[1][p])[w * 512 + l * 8] = *(const half8*)vs;
#endif
  };

  stage(0, 0);
  for (int c = 0; c < 32; ++c) {
    __syncthreads();  // drains chunk-c DMA (vmcnt(0) before barrier)
    if (c < 31) stage(c + 1, (c + 1) & 1);
    const int p = c & 1;

    half8 pb;
#pragma unroll
    for (int jt = 0; jt < 2; ++jt) {
      float4 k2v = *(const float4*)&k2b[c * 64 + jh * 32 + 16 * jt + 4 * quad];
      const short* kr = &sbuf[0][p][(jh * 32 + 16 * jt + l15) * 64];
      short8 k0 = *(const short8*)&kr[(quad ^ sx) << 3];
      short8 k1 = *(const short8*)&kr[((quad + 4) ^ sx) << 3];
      floatx4 a;  // accumulator pre-loaded with q2 + k2 (both CQ^2-scaled)
      a[0] = q2c + k2v.x;
      a[1] = q2c + k2v.y;
      a[2] = q2c + k2v.z;
      a[3] = q2c + k2v.w;
      __builtin_amdgcn_s_setprio(1);
      a = __builtin_amdgcn_mfma_f32_16x16x32_bf16(k0, qa0, a, 0, 0, 0);
      a = __builtin_amdgcn_mfma_f32_16x16x32_bf16(k1, qa1, a, 0, 0, 0);
      __builtin_amdgcn_s_setprio(0);
#pragma unroll
      for (int r = 0; r < 4; ++r) {
        float s = __builtin_amdgcn_sqrtf(fmaxf(a[r], EPS2_));
        float pv = __builtin_amdgcn_exp2f(-s);  // neg is a free input modifier
        lsum += pv;
        pb[4 * jt + r] = (_Float16)pv;
      }
    }

    __builtin_amdgcn_s_setprio(1);
#pragma unroll
    for (int dt = 0; dt < 4; ++dt) {
      const _Float16* vr = (const _Float16*)&sbuf[1][p][(16 * dt + l15) * 64];
      half8 hh = *(const half8*)&vr[((quad + 4 * jh) ^ sx) << 3];
      accO[dt] =
          __builtin_amdgcn_mfma_f32_16x16x32_f16(hh, pb, accO[dt], 0, 0, 0);
    }
    __builtin_amdgcn_s_setprio(0);
  }

  // Merge jh=1 partials into jh=0 through LDS (buffers are dead now).
  __syncthreads();
  float* scr = (float*)sbuf;  // 4 waves * 64 lanes * 17 floats = 17408B < 32KB
  const int sidx = (wr * 64 + l) * 17;
  if (jh) {
#pragma unroll
    for (int dt = 0; dt < 4; ++dt)
#pragma unroll
      for (int r = 0; r < 4; ++r) scr[sidx + dt * 4 + r] = accO[dt][r];
    scr[sidx + 16] = lsum;
  }
  __syncthreads();
  if (!jh) {
#pragma unroll
    for (int dt = 0; dt < 4; ++dt)
#pragma unroll
      for (int r = 0; r < 4; ++r) accO[dt][r] += scr[sidx + dt * 4 + r];
    lsum += scr[sidx + 16];
    lsum += __shfl_xor(lsum, 16);
    lsum += __shfl_xor(lsum, 32);
    float rl = 1.0f / lsum;
    size_t base = ((size_t)b * 2048 + i0 + 16 * wr + l15) * 512 + h * 64;
#pragma unroll
    for (int dt = 0; dt < 4; ++dt) {
      short4v pk;
#pragma unroll
      for (int r = 0; r < 4; ++r) pk[r] = bf16r(accO[dt][r] * rl);
      *(short4v*)&attn_t[base + 16 * dt + 4 * quad] = pk;
    }
  }
}

// ---------------------------------------------------------------------------
// Kernel 4: out-projection MFMA GEMM (R8 form, verified).
// 64o x 64n tiles, grid (32,4,B) = 512 blocks = 2 blocks/CU. 4 waves as 2x2:
// wave tile 32o x 32n, acc[2][2]. LDS 15.4KB.
// ---------------------------------------------------------------------------
__global__ __launch_bounds__(256) void outproj_kernel(
    const short* __restrict__ whi, const short* __restrict__ wlo,
    const short* __restrict__ Xt, float* __restrict__ Yf) {
  const int b = blockIdx.z;
  const int n0 = blockIdx.x * 64;
  const int o0 = blockIdx.y * 64;
  const int tid = threadIdx.x;
  const int w = tid >> 6, l = tid & 63, quad = l >> 4, l15 = l & 15;
  const int wo = (w >> 1) * 32, wn = (w & 1) * 32;

  __shared__ __align__(16) short Wa[2][64][40];
  __shared__ __align__(16) short Xb[64][40];

  floatx4 acc[2][2];
#pragma unroll
  for (int ot = 0; ot < 2; ++ot)
#pragma unroll
    for (int nt = 0; nt < 2; ++nt)
#pragma unroll
      for (int r = 0; r < 4; ++r) acc[ot][nt][r] = 0.f;

  for (int c0 = 0; c0 < 512; c0 += 32) {
    __syncthreads();
    {
      int row = tid >> 2, sg = (tid & 3) * 8;  // 64 rows x 32c in one pass
      size_t src = (size_t)(o0 + row) * 512 + c0 + sg;
      *(short8*)&Wa[0][row][sg] = *(const short8*)&whi[src];
      *(short8*)&Wa[1][row][sg] = *(const short8*)&wlo[src];
    }
    {
      int nn = tid >> 2, sg = (tid & 3) * 8;  // 64 rows x 32c in one pass
      *(short8*)&Xb[nn][sg] =
          *(const short8*)&Xt[((size_t)b * 2048 + n0 + nn) * 512 + c0 + sg];
    }
    __syncthreads();

    short8 ah[2], al[2], bx[2];
#pragma unroll
    for (int ot = 0; ot < 2; ++ot) {
      ah[ot] = *(const short8*)&Wa[0][wo + 16 * ot + l15][8 * quad];
      al[ot] = *(const short8*)&Wa[1][wo + 16 * ot + l15][8 * quad];
    }
#pragma unroll
    for (int nt = 0; nt < 2; ++nt)
      bx[nt] = *(const short8*)&Xb[wn + 16 * nt + l15][8 * quad];
#pragma unroll
    for (int ot = 0; ot < 2; ++ot)
#pragma unroll
      for (int nt = 0; nt < 2; ++nt) {
        acc[ot][nt] =
            __builtin_amdgcn_mfma_f32_16x16x32_bf16(al[ot], bx[nt], acc[ot][nt], 0, 0, 0);
        acc[ot][nt] =
            __builtin_amdgcn_mfma_f32_16x16x32_bf16(ah[ot], bx[nt], acc[ot][nt], 0, 0, 0);
      }
  }

#pragma unroll
  for (int ot = 0; ot < 2; ++ot)
#pragma unroll
    for (int r = 0; r < 4; ++r) {
      int o = o0 + wo + 16 * ot + 4 * quad + r;
#pragma unroll
      for (int nt = 0; nt < 2; ++nt)
        Yf[((size_t)b * 256 + o) * 2048 + n0 + wn + 16 * nt + l15] =
            acc[ot][nt][r];
    }
}

// ---------------------------------------------------------------------------
extern "C" void kernel_launch(void* const* d_in, const int* in_sizes, int n_in,
                              void* d_out, int out_size, void* d_ws,
                              size_t ws_size, hipStream_t stream) {
  const float* fmap = (const float*)d_in[0];
  const float* context = (const float*)d_in[1];
  const int* mask = (const int*)d_in[2];
  const float* gamma = (const float*)d_in[3];
  const float* gamma_ctx = (const float*)d_in[4];
  const float* Wq = (const float*)d_in[5];
  const float* Wkv = (const float*)d_in[6];
  const float* Wout = (const float*)d_in[7];
  float* out = (float*)d_out;

  char* ws = (char*)d_ws;
  short* fmap_t = (short*)ws;                 // 4 MB
  short* ctx_t = fmap_t + 2097152;            // 4 MB
  short* qb = ctx_t + 2097152;                // 8 MB
  short* kc = qb + 4194304;                   // 8 MB (-2CQ*K, swizzled tiles)
  _Float16* vc = (_Float16*)(kc + 4194304);   // 8 MB (f16, permuted tiles)
  short* attn_t = (short*)(vc + 4194304);     // 8 MB
  float* k2m = (float*)(attn_t + 4194304);    // 256 KB
  short* whi = (short*)(k2m + 65536);         // 1 MB
  short* wlo = whi + 524288;                  // 1 MB

  preproc_kernel<<<dim3(1024), 256, 0, stream>>>(
      Wq, Wkv, Wout, gamma, gamma_ctx, whi, wlo, fmap, context, fmap_t, ctx_t);
  qkv_gemm_kernel<<<dim3(16, 12, B_), 256, 0, stream>>>(
      whi, wlo, fmap_t, ctx_t, qb, kc, vc, mask, k2m);
  attn_kernel<<<dim3(1024), 512, 0, stream>>>(qb, kc, vc, k2m, attn_t);
  outproj_kernel<<<dim3(32, 4, B_), 256, 0, stream>>>(whi + 393216,
                                                      wlo + 393216, attn_t,
                                                      out);
}